// Round 3
// baseline (28603.287 us; speedup 1.0000x reference)
//
#include <hip/hip_runtime.h>
#include <hip/hip_bf16.h>

// ---------------- helpers ----------------
__device__ __forceinline__ int sgnf(float v){ return (v>0.f)-(v<0.f); }

// ---------------- conv1 7x7 s2 p3 + BN (no relu) ----------------
// x: (N,3,128,128), w: (64,3,7,7), out: (N,64,64,64)
__global__ void conv7_bn(const float* __restrict__ x, const float* __restrict__ w,
                         const float* __restrict__ gamma, const float* __restrict__ beta,
                         const float* __restrict__ mean, const float* __restrict__ var,
                         float* __restrict__ out, int N) {
    int idx = blockIdx.x*blockDim.x + threadIdx.x;
    int total = N<<18;
    if (idx >= total) return;
    int xo = idx & 63, yo = (idx>>6)&63, co = (idx>>12)&63, n = idx>>18;
    float acc = 0.f;
    const float* wp = w + co*147;
    const float* xp = x + (size_t)n*3*16384;
    for (int ci=0; ci<3; ++ci) {
        const float* xpc = xp + ci*16384;
        const float* wpc = wp + ci*49;
        #pragma unroll
        for (int ky=0; ky<7; ++ky) {
            int iy = yo*2 - 3 + ky;
            if ((unsigned)iy >= 128u) continue;
            const float* xrow = xpc + iy*128;
            const float* wrow = wpc + ky*7;
            #pragma unroll
            for (int kx=0; kx<7; ++kx) {
                int ix = xo*2 - 3 + kx;
                if ((unsigned)ix < 128u) acc += xrow[ix]*wrow[kx];
            }
        }
    }
    float inv = gamma[co] / sqrtf(var[co] + 1e-5f);
    out[idx] = (acc - mean[co])*inv + beta[co];
}

// ---------------- generic 3x3 conv + relu ----------------
__global__ void conv3_relu(const float* __restrict__ in, const float* __restrict__ w,
                           float* __restrict__ out,
                           int N, int Ci, int Co, int Hi, int Wi, int Ho, int Wo, int stride) {
    int idx = blockIdx.x*blockDim.x + threadIdx.x;
    int total = N*Co*Ho*Wo;
    if (idx >= total) return;
    int xo = idx % Wo; int t = idx / Wo;
    int yo = t % Ho;   t /= Ho;
    int co = t % Co;   int n = t / Co;
    const float* wp = w + (size_t)co*Ci*9;
    const float* ip = in + (size_t)n*Ci*Hi*Wi;
    int iy0 = yo*stride - 1, ix0 = xo*stride - 1;
    float acc = 0.f;
    for (int ci=0; ci<Ci; ++ci) {
        const float* ipc = ip + (size_t)ci*Hi*Wi;
        const float* wpc = wp + ci*9;
        #pragma unroll
        for (int ky=0; ky<3; ++ky) {
            int iy = iy0 + ky;
            if ((unsigned)iy >= (unsigned)Hi) continue;
            const float* r = ipc + iy*Wi;
            #pragma unroll
            for (int kx=0; kx<3; ++kx) {
                int ix = ix0 + kx;
                if ((unsigned)ix < (unsigned)Wi) acc += r[ix]*wpc[ky*3+kx];
            }
        }
    }
    out[idx] = fmaxf(acc, 0.f);
}

// ---------------- spatial mean over HW ----------------
__global__ void spatial_mean(const float* __restrict__ in, float* __restrict__ out,
                             int rows, int HW) {
    int idx = blockIdx.x*blockDim.x + threadIdx.x;
    if (idx >= rows) return;
    const float* p = in + (size_t)idx*HW;
    float s = 0.f;
    for (int i=0;i<HW;++i) s += p[i];
    out[idx] = s / (float)HW;
}

// ---------------- classifier head: sigmoid(mean @ cw.T + b) ----------------
__global__ void head_sigmoid(const float* __restrict__ m, const float* __restrict__ cw,
                             const float* __restrict__ cb, float* __restrict__ out0,
                             float* __restrict__ out1, int Nrows) {
    int idx = blockIdx.x*blockDim.x + threadIdx.x;
    if (idx >= Nrows*20) return;
    int o = idx % 20, n = idx / 20;
    const float* mp = m + (size_t)n*1024;
    const float* wp = cw + (size_t)o*1024;
    float s = cb[o];
    for (int c=0;c<1024;++c) s += mp[c]*wp[c];
    float v = 1.f/(1.f+expf(-s));
    out0[idx] = v;
    if (out1) out1[idx] = v;
}

// ---------------- cam: sigmoid(act . cw + b) per pixel ----------------
// act: (N,1024,8,8), cam: (N,20,8,8)
__global__ void cam_kernel(const float* __restrict__ act, const float* __restrict__ cw,
                           const float* __restrict__ cb, float* __restrict__ cam, int N) {
    int idx = blockIdx.x*blockDim.x + threadIdx.x;
    if (idx >= N*20*64) return;
    int p = idx & 63; int o = (idx>>6) % 20; int n = idx / 1280;
    const float* a = act + (size_t)n*1024*64 + p;
    const float* wp = cw + (size_t)o*1024;
    float s = cb[o];
    for (int c=0;c<1024;++c) s += a[c*64]*wp[c];
    cam[idx] = 1.f/(1.f+expf(-s));
}

// ---------------- bilinear resize cam (8x8 -> 128x128, align-corners) ----------------
__global__ void resize_cam(const float* __restrict__ cam, float* __restrict__ cs, int N) {
    int idx = blockIdx.x*blockDim.x + threadIdx.x;
    if (idx >= N*20*16384) return;
    int xo = idx & 127, yo = (idx>>7)&127;
    int bo = idx >> 14;           // n*20+o
    float fy = (float)yo * (7.0f/127.0f);
    float fx = (float)xo * (7.0f/127.0f);
    int y0 = (int)floorf(fy); float wy = fy - (float)y0;
    int x0 = (int)floorf(fx); float wx = fx - (float)x0;
    if (y0 > 7) y0 = 7; if (y0 < 0) y0 = 0; int y1 = min(y0+1, 7);
    if (x0 > 7) x0 = 7; if (x0 < 0) x0 = 0; int x1 = min(x0+1, 7);
    const float* c = cam + (size_t)bo*64;
    float v = (1.f-wy)*((1.f-wx)*c[y0*8+x0] + wx*c[y0*8+x1])
            +      wy *((1.f-wx)*c[y1*8+x0] + wx*c[y1*8+x1]);
    cs[idx] = v;
}

// ---------------- wscore = max over h, hscore = max over w ----------------
__global__ void score_maxred(const float* __restrict__ cs, float* __restrict__ wsc,
                             float* __restrict__ hsc, int N) {
    int idx = blockIdx.x*blockDim.x + threadIdx.x;
    int total = N*20*128;
    if (idx >= 2*total) return;
    if (idx < total) {
        int wcol = idx % 128; int bo = idx / 128;
        const float* p = cs + (size_t)bo*16384 + wcol;
        float mv = -1e30f;
        for (int h=0; h<128; ++h) mv = fmaxf(mv, p[h*128]);
        wsc[idx] = mv;
    } else {
        int i = idx - total;
        int hrow = i % 128; int bo = i / 128;
        const float* p = cs + (size_t)bo*16384 + hrow*128;
        float mv = -1e30f;
        for (int w_=0; w_<128; ++w_) mv = fmaxf(mv, p[w_]);
        hsc[i] = mv;
    }
}

// ---------------- stable top-4 of 20 per batch ----------------
__global__ void topk4(const float* __restrict__ gs, int* __restrict__ top, int N) {
    int n = threadIdx.x;
    if (n >= N) return;
    const float* g = gs + n*20;
    bool used[20];
    for (int i=0;i<20;++i) used[i]=false;
    for (int t=0;t<4;++t) {
        int bi = -1; float bv = -1e30f;
        for (int i=0;i<20;++i) {
            if (!used[i] && g[i] > bv) { bv = g[i]; bi = i; }
        }
        used[bi] = true;
        top[n*4+t] = bi;
    }
}

// ---------------- gather top rows + norm01 ----------------
__global__ void gather_norm(const float* __restrict__ wsc, const float* __restrict__ hsc,
                            const int* __restrict__ top, float* __restrict__ xs,
                            float* __restrict__ ysn, int N) {
    int r = blockIdx.x;
    int axis = r / (N*4); int row = r % (N*4);
    int b = row / 4;
    int cls = top[row];
    const float* src = (axis==0 ? wsc : hsc) + ((size_t)b*20 + cls)*128;
    int t = threadIdx.x;
    float v = src[t];
    __shared__ float smn[128], smx[128];
    smn[t] = v; smx[t] = v;
    __syncthreads();
    for (int off=64; off>0; off>>=1) {
        if (t < off) { smn[t] = fminf(smn[t], smn[t+off]); smx[t] = fmaxf(smx[t], smx[t+off]); }
        __syncthreads();
    }
    float mn = smn[0], mx = smx[0];
    float outv;
    if (mx == mn) outv = v / (mx == 0.f ? 1.f : mx);
    else          outv = (v - mn) / (mx - mn);
    (axis==0 ? xs : ysn)[row*128 + t] = outv;
}

// ---------------- obj_loc (sequential per row, 64 threads) ----------------
__global__ void objloc(const float* __restrict__ xs, const float* __restrict__ ysn,
                       int* __restrict__ box, int N) {
    int i = threadIdx.x;
    if (i >= 2*N*4) return;
    int axis = i / (N*4); int row = i % (N*4);
    const float* s = (axis ? ysn : xs) + (size_t)row*128;
    const int S = 128, minsize = 16;
    int pos[127]; int ncross = 0;
    int prev = sgnf(s[0] - 0.5f);
    for (int k=1; k<S; ++k) {
        int cur = sgnf(s[k] - 0.5f);
        int d = cur - prev; if (d < 0) d = -d;
        if (d == 2) pos[ncross++] = k-1;
        prev = cur;
    }
    float m = -1e30f;
    for (int k=0; k<S; ++k) m = fmaxf(m, s[k]);
    int zmin = 0, zmax = S, bestkey = -2;
    int a = 0;
    for (int j=0; j<=ncross; ++j) {
        int bnd = (j < ncross) ? pos[j] : S;
        float sm = -1e30f;
        for (int k=a; k<bnd; ++k) sm = fmaxf(sm, s[k]);
        int len = bnd - a;
        int key = (sm == m) ? len : -1;
        if (key > bestkey) { bestkey = key; zmin = a; zmax = bnd; }
        a = bnd;
    }
    bool need = (zmax - zmin) <= minsize;
    int pad = minsize - (zmax - zmin);
    int cp = (pad + 1) >> 1;   // pad >= 0 whenever used
    bool c1 = need && (zmin > cp) && (S - zmax > pad);
    if (c1) { zmin = zmin - cp + 1; zmax = zmax + cp; }
    bool c2 = need && (zmin < cp);
    if (c2) { zmin = 0; zmax = minsize; }
    bool c3 = need && (S - zmax < cp);
    if (c3) { zmin = S - minsize + 1; zmax = S; }
    if (ncross == 0) { zmin = minsize; zmax = 112; }
    if (axis == 0) { box[row] = zmin; box[32+row] = zmax; }
    else           { box[64+row] = zmin; box[96+row] = zmax; }
}

// ---------------- crop + bilinear resize to 128x128 ----------------
// x: (B,3,128,128), out: (B*4,3,128,128)
__global__ void crop_resize_k(const float* __restrict__ x, const int* __restrict__ box,
                              float* __restrict__ lin, int N) {
    int idx = blockIdx.x*blockDim.x + threadIdx.x;
    if (idx >= N*4*3*16384) return;
    int xo = idx & 127, yo = (idx>>7)&127;
    int c  = (idx>>14) % 3;
    int r  = idx / 49152;       // b*4+t
    int b  = r / 4;
    int cx1 = box[r],    cx2 = box[32+r];
    int cy1 = box[64+r], cy2 = box[96+r];
    float fy = (float)cy1 + (float)(yo * (cy2 - 1 - cy1)) / 127.0f;
    float fx = (float)cx1 + (float)(xo * (cx2 - 1 - cx1)) / 127.0f;
    float wy = fy - floorf(fy);
    float wx = fx - floorf(fx);
    int y0 = min(max((int)floorf(fy), 0), 127); int y1 = min(y0 + 1, 127);
    int x0 = min(max((int)floorf(fx), 0), 127); int x1 = min(x0 + 1, 127);
    const float* img = x + ((size_t)b*3 + c)*16384;
    float v = (1.f-wy)*((1.f-wx)*img[y0*128+x0] + wx*img[y0*128+x1])
            +      wy *((1.f-wx)*img[y1*128+x0] + wx*img[y1*128+x1]);
    lin[idx] = v;
}

// ---------------- local_stream = max over TOPN ----------------
__global__ void local_stream_max(const float* __restrict__ loc, float* __restrict__ out, int N) {
    int idx = threadIdx.x;
    if (idx >= N*20) return;
    int o = idx % 20, b = idx / 20;
    float mv = -1e30f;
    for (int t=0; t<4; ++t) mv = fmaxf(mv, loc[((size_t)(b*4+t))*20 + o]);
    out[idx] = mv;
}

// ---------------- launcher ----------------
extern "C" void kernel_launch(void* const* d_in, const int* in_sizes, int n_in,
                              void* d_out_, int out_size, void* d_ws, size_t ws_size,
                              hipStream_t stream) {
    const float* x    = (const float*)d_in[0];
    const float* c1w  = (const float*)d_in[1];
    const float* bng  = (const float*)d_in[2];
    const float* bnb  = (const float*)d_in[3];
    const float* bnm  = (const float*)d_in[4];
    const float* bnv  = (const float*)d_in[5];
    const float* w1   = (const float*)d_in[6];
    const float* w2   = (const float*)d_in[7];
    const float* w3   = (const float*)d_in[8];
    const float* w4   = (const float*)d_in[9];
    const float* clsw = (const float*)d_in[10];
    const float* clsb = (const float*)d_in[11];
    float* dout = (float*)d_out_;
    float* ws   = (float*)d_ws;

    // output layout (f32 elements, concatenated in return order)
    float* out_gs = dout + 0;         // (8,20)           160
    float* out_ls = dout + 160;       // (8,20)           160
    float* out_cs = dout + 320;       // (8,20,128,128)   2,621,440
    float* out_ws = dout + 2621760;   // (8,20,128)       20,480
    float* out_hs = dout + 2642240;   // (8,20,128)       20,480
    float* out_li = dout + 2662720;   // (32,3,128,128)   1,572,864

    // workspace layout (floats) — ~6.9M floats (~27.5 MB)
    float* bufA  = ws + 0;          // 2,097,152
    float* bufB  = ws + 2097152;    // 4,194,304
    float* act   = ws + 6291456;    // 524,288
    float* gmean = ws + 6815744;    // 8,192
    float* gst   = ws + 6823936;    // 160
    float* cam   = ws + 6824096;    // 10,240
    int*   top   = (int*)(ws + 6834336); // 32
    float* xs    = ws + 6834368;    // 4,096
    float* ysn   = ws + 6838464;    // 4,096
    int*   box   = (int*)(ws + 6842560); // 128
    float* lmean = ws + 6842688;    // 32,768
    float* locf  = ws + 6875456;    // 640

    // ---- global branch ----
    conv7_bn<<<8192,256,0,stream>>>(x, c1w, bng, bnb, bnm, bnv, bufA, 8);
    conv3_relu<<<16384,256,0,stream>>>(bufA, w1, bufB, 8,  64, 128, 64,64, 64,64, 1);
    conv3_relu<<< 8192,256,0,stream>>>(bufB, w2, bufA, 8, 128, 256, 64,64, 32,32, 2);
    conv3_relu<<< 4096,256,0,stream>>>(bufA, w3, bufB, 8, 256, 512, 32,32, 16,16, 2);
    conv3_relu<<< 2048,256,0,stream>>>(bufB, w4, act,  8, 512,1024, 16,16,  8, 8, 2);
    spatial_mean<<<32,256,0,stream>>>(act, gmean, 8192, 64);
    head_sigmoid<<<1,256,0,stream>>>(gmean, clsw, clsb, gst, out_gs, 8);
    cam_kernel<<<40,256,0,stream>>>(act, clsw, clsb, cam, 8);
    resize_cam<<<10240,256,0,stream>>>(cam, out_cs, 8);
    score_maxred<<<160,256,0,stream>>>(out_cs, out_ws, out_hs, 8);
    topk4<<<1,64,0,stream>>>(gst, top, 8);
    gather_norm<<<64,128,0,stream>>>(out_ws, out_hs, top, xs, ysn, 8);
    objloc<<<1,64,0,stream>>>(xs, ysn, box, 8);
    crop_resize_k<<<6144,256,0,stream>>>(x, box, out_li, 8);

    // ---- local branch: 4 chunks of 8 images ----
    for (int c = 0; c < 4; ++c) {
        const float* lin_c = out_li + (size_t)c*8*3*16384;
        conv7_bn<<<8192,256,0,stream>>>(lin_c, c1w, bng, bnb, bnm, bnv, bufA, 8);
        conv3_relu<<<16384,256,0,stream>>>(bufA, w1, bufB, 8,  64, 128, 64,64, 64,64, 1);
        conv3_relu<<< 8192,256,0,stream>>>(bufB, w2, bufA, 8, 128, 256, 64,64, 32,32, 2);
        conv3_relu<<< 4096,256,0,stream>>>(bufA, w3, bufB, 8, 256, 512, 32,32, 16,16, 2);
        conv3_relu<<< 2048,256,0,stream>>>(bufB, w4, act,  8, 512,1024, 16,16,  8, 8, 2);
        spatial_mean<<<32,256,0,stream>>>(act, lmean + c*8192, 8192, 64);
    }
    head_sigmoid<<<3,256,0,stream>>>(lmean, clsw, clsb, locf, (float*)nullptr, 32);
    local_stream_max<<<1,256,0,stream>>>(locf, out_ls, 8);
}

// Round 4
// 3696.904 us; speedup vs baseline: 7.7371x; 7.7371x over previous
//
#include <hip/hip_runtime.h>
#include <hip/hip_bf16.h>

// ---------------- helpers ----------------
__device__ __forceinline__ int sgnf(float v){ return (v>0.f)-(v<0.f); }

// =====================================================================
// Tiled 3x3 conv + relu.  in:(N,Ci,Hi,Wi) f32, w:(Co,Ci,3,3), out:(N,Co,Ho,Wo)
// Each thread: 2x4 output sub-tile for one co. LDS-staged input+weights.
// =====================================================================
template<int STRIDE, int TH, int TW, int CO_T, int CI_T, int NT>
__global__ __launch_bounds__(NT) void conv3_tiled(
    const float* __restrict__ in, const float* __restrict__ w, float* __restrict__ out,
    int N, int Ci, int Co, int Hi, int Wi, int Ho, int Wo)
{
    constexpr int NSP   = (TH/2)*(TW/4);
    constexpr int IT_H  = (TH-1)*STRIDE + 3;
    constexpr int IT_W  = (TW-1)*STRIDE + 3;
    constexpr int ITW_P = (IT_W + 3) & ~3;       // row stride, 16B-aligned
    constexpr int IN_ELEMS = CI_T*IT_H*IT_W;
    constexpr int W_ELEMS  = CI_T*CO_T*9;
    static_assert(NSP*CO_T == NT, "thread count mismatch");

    __shared__ float s_in[CI_T*IT_H*ITW_P];
    __shared__ float s_w[CI_T*CO_T*12];

    int bx = blockIdx.x;
    const int spxn = Wo/TW, spyn = Ho/TH, cog = Co/CO_T;
    const int sxb = bx % spxn; bx /= spxn;
    const int syb = bx % spyn; bx /= spyn;
    const int cg  = bx % cog;  const int n = bx / cog;
    const int tx0 = sxb*TW, ty0 = syb*TH, co0 = cg*CO_T;

    const int tid = threadIdx.x;
    const int sp  = tid % NSP;
    const int co  = tid / NSP;
    const int sy  = (sp / (TW/4)) * 2;
    const int sx  = (sp % (TW/4)) * 4;

    const int y_in0 = ty0*STRIDE - 1, x_in0 = tx0*STRIDE - 1;
    const float* in_n = in + (size_t)n*Ci*Hi*Wi;

    float acc[2][4] = {{0.f,0.f,0.f,0.f},{0.f,0.f,0.f,0.f}};

    for (int ci0 = 0; ci0 < Ci; ci0 += CI_T) {
        // ---- stage input tile ----
        for (int idx = tid; idx < IN_ELEMS; idx += NT) {
            int ci  = idx / (IT_H*IT_W);
            int rem = idx - ci*(IT_H*IT_W);
            int iy  = rem / IT_W;
            int ix  = rem - iy*IT_W;
            int gy = y_in0 + iy, gx = x_in0 + ix;
            float v = 0.f;
            if ((unsigned)gy < (unsigned)Hi && (unsigned)gx < (unsigned)Wi)
                v = in_n[(size_t)(ci0+ci)*Hi*Wi + gy*Wi + gx];
            s_in[ci*(IT_H*ITW_P) + iy*ITW_P + ix] = v;
        }
        // ---- stage weights ----
        for (int idx = tid; idx < W_ELEMS; idx += NT) {
            int ci  = idx / (CO_T*9);
            int rem = idx - ci*(CO_T*9);
            int c   = rem / 9, k = rem - c*9;
            s_w[(ci*CO_T + c)*12 + k] = w[((size_t)(co0+c)*Ci + (ci0+ci))*9 + k];
        }
        __syncthreads();

        for (int ci = 0; ci < CI_T; ++ci) {
            const float* wp = &s_w[(ci*CO_T + co)*12];
            float wr[9];
            *(float4*)&wr[0] = *(const float4*)&wp[0];
            *(float4*)&wr[4] = *(const float4*)&wp[4];
            wr[8] = wp[8];
            const float* ip = &s_in[ci*(IT_H*ITW_P)];
            if (STRIDE == 1) {
                float r[4][6];
                #pragma unroll
                for (int rr = 0; rr < 4; ++rr) {
                    const float* row = ip + (sy+rr)*ITW_P + sx;
                    *(float4*)&r[rr][0] = *(const float4*)&row[0];
                    *(float2*)&r[rr][4] = *(const float2*)&row[4];
                }
                #pragma unroll
                for (int ry=0; ry<2; ++ry)
                  #pragma unroll
                  for (int ky=0; ky<3; ++ky)
                    #pragma unroll
                    for (int kx=0; kx<3; ++kx)
                      #pragma unroll
                      for (int rx=0; rx<4; ++rx)
                        acc[ry][rx] += r[ry+ky][rx+kx] * wr[ky*3+kx];
            } else {
                float r[5][9];
                #pragma unroll
                for (int rr = 0; rr < 5; ++rr) {
                    const float* row = ip + (2*sy+rr)*ITW_P + 2*sx;
                    *(float4*)&r[rr][0] = *(const float4*)&row[0];
                    *(float4*)&r[rr][4] = *(const float4*)&row[4];
                    r[rr][8] = row[8];
                }
                #pragma unroll
                for (int ry=0; ry<2; ++ry)
                  #pragma unroll
                  for (int ky=0; ky<3; ++ky)
                    #pragma unroll
                    for (int kx=0; kx<3; ++kx)
                      #pragma unroll
                      for (int rx=0; rx<4; ++rx)
                        acc[ry][rx] += r[2*ry+ky][2*rx+kx] * wr[ky*3+kx];
            }
        }
        __syncthreads();
    }

    // ---- epilogue: relu + store ----
    float* op = out + ((size_t)n*Co + co0 + co)*Ho*Wo + (size_t)(ty0+sy)*Wo + (tx0+sx);
    #pragma unroll
    for (int ry=0; ry<2; ++ry) {
        float4 v;
        v.x = fmaxf(acc[ry][0], 0.f); v.y = fmaxf(acc[ry][1], 0.f);
        v.z = fmaxf(acc[ry][2], 0.f); v.w = fmaxf(acc[ry][3], 0.f);
        *(float4*)(op + (size_t)ry*Wo) = v;
    }
}

// =====================================================================
// Tiled 7x7 s2 p3 conv + BN. x:(N,3,128,128), w:(64,3,7,7), out:(N,64,64,64)
// TH=TW=16, CO_T=8, 256 threads, Ci=3 staged once.
// =====================================================================
__global__ __launch_bounds__(256) void conv7_bn_tiled(
    const float* __restrict__ x, const float* __restrict__ w,
    const float* __restrict__ gamma, const float* __restrict__ beta,
    const float* __restrict__ mean, const float* __restrict__ var,
    float* __restrict__ out, int N)
{
    constexpr int TH=16, TW=16, CO_T=8, NT=256, NSP=32;
    constexpr int IT = (TH-1)*2 + 7;          // 37
    constexpr int ITW_P = 40;
    constexpr int IN_ELEMS = 3*IT*IT;         // 4107
    constexpr int W_ELEMS  = CO_T*3*49;       // 1176

    __shared__ float s_in[3*IT*ITW_P];
    __shared__ float s_w[CO_T*3*7*8];

    int bx = blockIdx.x;
    const int spn = 64/TW;                    // 4
    const int cog = 64/CO_T;                  // 8
    const int sxb = bx % spn; bx /= spn;
    const int syb = bx % spn; bx /= spn;
    const int cg  = bx % cog; const int n = bx / cog;
    const int tx0 = sxb*TW, ty0 = syb*TH, co0 = cg*CO_T;

    const int tid = threadIdx.x;
    const int sp  = tid % NSP;
    const int co  = tid / NSP;
    const int sy  = (sp / (TW/4)) * 2;
    const int sx  = (sp % (TW/4)) * 4;

    const int y_in0 = ty0*2 - 3, x_in0 = tx0*2 - 3;
    const float* x_n = x + (size_t)n*3*16384;

    // stage input
    for (int idx = tid; idx < IN_ELEMS; idx += NT) {
        int ci  = idx / (IT*IT);
        int rem = idx - ci*(IT*IT);
        int iy  = rem / IT;
        int ix  = rem - iy*IT;
        int gy = y_in0 + iy, gx = x_in0 + ix;
        float v = 0.f;
        if ((unsigned)gy < 128u && (unsigned)gx < 128u)
            v = x_n[(size_t)ci*16384 + gy*128 + gx];
        s_in[ci*(IT*ITW_P) + iy*ITW_P + ix] = v;
    }
    // stage weights: layout [co][ci][ky][8]
    for (int idx = tid; idx < W_ELEMS; idx += NT) {
        int c   = idx / 147;
        int rem = idx - c*147;
        int ci  = rem / 49;
        int rem2= rem - ci*49;
        int ky  = rem2 / 7, kx = rem2 - ky*7;
        s_w[((c*3 + ci)*7 + ky)*8 + kx] = w[(size_t)(co0+c)*147 + ci*49 + ky*7 + kx];
    }
    __syncthreads();

    float acc[2][4] = {{0.f,0.f,0.f,0.f},{0.f,0.f,0.f,0.f}};
    const int c0 = 2*sx;
    for (int ci = 0; ci < 3; ++ci) {
        const float* ip = &s_in[ci*(IT*ITW_P)];
        #pragma unroll
        for (int ky = 0; ky < 7; ++ky) {
            float wr[7];
            const float* wp = &s_w[((co*3 + ci)*7 + ky)*8];
            *(float4*)&wr[0] = *(const float4*)&wp[0];
            *(float2*)&wr[4] = *(const float2*)&wp[4];
            wr[6] = wp[6];
            float r[2][13];
            #pragma unroll
            for (int ry = 0; ry < 2; ++ry) {
                const float* row = ip + (2*sy + 2*ry + ky)*ITW_P + c0;
                *(float4*)&r[ry][0] = *(const float4*)&row[0];
                *(float4*)&r[ry][4] = *(const float4*)&row[4];
                *(float4*)&r[ry][8] = *(const float4*)&row[8];
                r[ry][12] = row[12];
            }
            #pragma unroll
            for (int ry=0; ry<2; ++ry)
              #pragma unroll
              for (int kx=0; kx<7; ++kx)
                #pragma unroll
                for (int rx=0; rx<4; ++rx)
                  acc[ry][rx] += r[ry][2*rx+kx] * wr[kx];
        }
    }

    const int coo = co0 + co;
    float inv = gamma[coo] / sqrtf(var[coo] + 1e-5f);
    float mu = mean[coo], bb = beta[coo];
    float* op = out + ((size_t)n*64 + coo)*4096 + (size_t)(ty0+sy)*64 + (tx0+sx);
    #pragma unroll
    for (int ry=0; ry<2; ++ry) {
        float4 v;
        v.x = (acc[ry][0]-mu)*inv + bb; v.y = (acc[ry][1]-mu)*inv + bb;
        v.z = (acc[ry][2]-mu)*inv + bb; v.w = (acc[ry][3]-mu)*inv + bb;
        *(float4*)(op + (size_t)ry*64) = v;
    }
}

// ---------------- spatial mean over HW ----------------
__global__ void spatial_mean(const float* __restrict__ in, float* __restrict__ out,
                             int rows, int HW) {
    int idx = blockIdx.x*blockDim.x + threadIdx.x;
    if (idx >= rows) return;
    const float* p = in + (size_t)idx*HW;
    float s = 0.f;
    for (int i=0;i<HW;++i) s += p[i];
    out[idx] = s / (float)HW;
}

// ---------------- classifier head: sigmoid(mean @ cw.T + b) ----------------
__global__ void head_sigmoid(const float* __restrict__ m, const float* __restrict__ cw,
                             const float* __restrict__ cb, float* __restrict__ out0,
                             float* __restrict__ out1, int Nrows) {
    int idx = blockIdx.x*blockDim.x + threadIdx.x;
    if (idx >= Nrows*20) return;
    int o = idx % 20, n = idx / 20;
    const float* mp = m + (size_t)n*1024;
    const float* wp = cw + (size_t)o*1024;
    float s = cb[o];
    for (int c=0;c<1024;++c) s += mp[c]*wp[c];
    float v = 1.f/(1.f+expf(-s));
    out0[idx] = v;
    if (out1) out1[idx] = v;
}

// ---------------- cam: sigmoid(act . cw + b) per pixel ----------------
__global__ void cam_kernel(const float* __restrict__ act, const float* __restrict__ cw,
                           const float* __restrict__ cb, float* __restrict__ cam, int N) {
    int idx = blockIdx.x*blockDim.x + threadIdx.x;
    if (idx >= N*20*64) return;
    int p = idx & 63; int o = (idx>>6) % 20; int n = idx / 1280;
    const float* a = act + (size_t)n*1024*64 + p;
    const float* wp = cw + (size_t)o*1024;
    float s = cb[o];
    for (int c=0;c<1024;++c) s += a[c*64]*wp[c];
    cam[idx] = 1.f/(1.f+expf(-s));
}

// ---------------- bilinear resize cam (8x8 -> 128x128, align-corners) ----------------
__global__ void resize_cam(const float* __restrict__ cam, float* __restrict__ cs, int N) {
    int idx = blockIdx.x*blockDim.x + threadIdx.x;
    if (idx >= N*20*16384) return;
    int xo = idx & 127, yo = (idx>>7)&127;
    int bo = idx >> 14;
    float fy = (float)yo * (7.0f/127.0f);
    float fx = (float)xo * (7.0f/127.0f);
    int y0 = (int)floorf(fy); float wy = fy - (float)y0;
    int x0 = (int)floorf(fx); float wx = fx - (float)x0;
    if (y0 > 7) y0 = 7; if (y0 < 0) y0 = 0; int y1 = min(y0+1, 7);
    if (x0 > 7) x0 = 7; if (x0 < 0) x0 = 0; int x1 = min(x0+1, 7);
    const float* c = cam + (size_t)bo*64;
    float v = (1.f-wy)*((1.f-wx)*c[y0*8+x0] + wx*c[y0*8+x1])
            +      wy *((1.f-wx)*c[y1*8+x0] + wx*c[y1*8+x1]);
    cs[idx] = v;
}

// ---------------- wscore / hscore max reductions ----------------
__global__ void score_maxred(const float* __restrict__ cs, float* __restrict__ wsc,
                             float* __restrict__ hsc, int N) {
    int idx = blockIdx.x*blockDim.x + threadIdx.x;
    int total = N*20*128;
    if (idx >= 2*total) return;
    if (idx < total) {
        int wcol = idx % 128; int bo = idx / 128;
        const float* p = cs + (size_t)bo*16384 + wcol;
        float mv = -1e30f;
        for (int h=0; h<128; ++h) mv = fmaxf(mv, p[h*128]);
        wsc[idx] = mv;
    } else {
        int i = idx - total;
        int hrow = i % 128; int bo = i / 128;
        const float* p = cs + (size_t)bo*16384 + hrow*128;
        float mv = -1e30f;
        for (int w_=0; w_<128; ++w_) mv = fmaxf(mv, p[w_]);
        hsc[i] = mv;
    }
}

// ---------------- stable top-4 of 20 per batch ----------------
__global__ void topk4(const float* __restrict__ gs, int* __restrict__ top, int N) {
    int n = threadIdx.x;
    if (n >= N) return;
    const float* g = gs + n*20;
    bool used[20];
    for (int i=0;i<20;++i) used[i]=false;
    for (int t=0;t<4;++t) {
        int bi = -1; float bv = -1e30f;
        for (int i=0;i<20;++i) {
            if (!used[i] && g[i] > bv) { bv = g[i]; bi = i; }
        }
        used[bi] = true;
        top[n*4+t] = bi;
    }
}

// ---------------- gather top rows + norm01 ----------------
__global__ void gather_norm(const float* __restrict__ wsc, const float* __restrict__ hsc,
                            const int* __restrict__ top, float* __restrict__ xs,
                            float* __restrict__ ysn, int N) {
    int r = blockIdx.x;
    int axis = r / (N*4); int row = r % (N*4);
    int b = row / 4;
    int cls = top[row];
    const float* src = (axis==0 ? wsc : hsc) + ((size_t)b*20 + cls)*128;
    int t = threadIdx.x;
    float v = src[t];
    __shared__ float smn[128], smx[128];
    smn[t] = v; smx[t] = v;
    __syncthreads();
    for (int off=64; off>0; off>>=1) {
        if (t < off) { smn[t] = fminf(smn[t], smn[t+off]); smx[t] = fmaxf(smx[t], smx[t+off]); }
        __syncthreads();
    }
    float mn = smn[0], mx = smx[0];
    float outv;
    if (mx == mn) outv = v / (mx == 0.f ? 1.f : mx);
    else          outv = (v - mn) / (mx - mn);
    (axis==0 ? xs : ysn)[row*128 + t] = outv;
}

// ---------------- obj_loc (sequential per row) ----------------
__global__ void objloc(const float* __restrict__ xs, const float* __restrict__ ysn,
                       int* __restrict__ box, int N) {
    int i = threadIdx.x;
    if (i >= 2*N*4) return;
    int axis = i / (N*4); int row = i % (N*4);
    const float* s = (axis ? ysn : xs) + (size_t)row*128;
    const int S = 128, minsize = 16;
    int pos[127]; int ncross = 0;
    int prev = sgnf(s[0] - 0.5f);
    for (int k=1; k<S; ++k) {
        int cur = sgnf(s[k] - 0.5f);
        int d = cur - prev; if (d < 0) d = -d;
        if (d == 2) pos[ncross++] = k-1;
        prev = cur;
    }
    float m = -1e30f;
    for (int k=0; k<S; ++k) m = fmaxf(m, s[k]);
    int zmin = 0, zmax = S, bestkey = -2;
    int a = 0;
    for (int j=0; j<=ncross; ++j) {
        int bnd = (j < ncross) ? pos[j] : S;
        float sm = -1e30f;
        for (int k=a; k<bnd; ++k) sm = fmaxf(sm, s[k]);
        int len = bnd - a;
        int key = (sm == m) ? len : -1;
        if (key > bestkey) { bestkey = key; zmin = a; zmax = bnd; }
        a = bnd;
    }
    bool need = (zmax - zmin) <= minsize;
    int pad = minsize - (zmax - zmin);
    int cp = (pad + 1) >> 1;
    bool c1 = need && (zmin > cp) && (S - zmax > pad);
    if (c1) { zmin = zmin - cp + 1; zmax = zmax + cp; }
    bool c2 = need && (zmin < cp);
    if (c2) { zmin = 0; zmax = minsize; }
    bool c3 = need && (S - zmax < cp);
    if (c3) { zmin = S - minsize + 1; zmax = S; }
    if (ncross == 0) { zmin = minsize; zmax = 112; }
    if (axis == 0) { box[row] = zmin; box[32+row] = zmax; }
    else           { box[64+row] = zmin; box[96+row] = zmax; }
}

// ---------------- crop + bilinear resize to 128x128 ----------------
__global__ void crop_resize_k(const float* __restrict__ x, const int* __restrict__ box,
                              float* __restrict__ lin, int N) {
    int idx = blockIdx.x*blockDim.x + threadIdx.x;
    if (idx >= N*4*3*16384) return;
    int xo = idx & 127, yo = (idx>>7)&127;
    int c  = (idx>>14) % 3;
    int r  = idx / 49152;
    int b  = r / 4;
    int cx1 = box[r],    cx2 = box[32+r];
    int cy1 = box[64+r], cy2 = box[96+r];
    float fy = (float)cy1 + (float)(yo * (cy2 - 1 - cy1)) / 127.0f;
    float fx = (float)cx1 + (float)(xo * (cx2 - 1 - cx1)) / 127.0f;
    float wy = fy - floorf(fy);
    float wx = fx - floorf(fx);
    int y0 = min(max((int)floorf(fy), 0), 127); int y1 = min(y0 + 1, 127);
    int x0 = min(max((int)floorf(fx), 0), 127); int x1 = min(x0 + 1, 127);
    const float* img = x + ((size_t)b*3 + c)*16384;
    float v = (1.f-wy)*((1.f-wx)*img[y0*128+x0] + wx*img[y0*128+x1])
            +      wy *((1.f-wx)*img[y1*128+x0] + wx*img[y1*128+x1]);
    lin[idx] = v;
}

// ---------------- local_stream = max over TOPN ----------------
__global__ void local_stream_max(const float* __restrict__ loc, float* __restrict__ out, int N) {
    int idx = threadIdx.x;
    if (idx >= N*20) return;
    int o = idx % 20, b = idx / 20;
    float mv = -1e30f;
    for (int t=0; t<4; ++t) mv = fmaxf(mv, loc[((size_t)(b*4+t))*20 + o]);
    out[idx] = mv;
}

// ---------------- conv stack helper ----------------
static void run_feature_stack(const float* input, int n,
                              const float* c1w, const float* bng, const float* bnb,
                              const float* bnm, const float* bnv,
                              const float* w1, const float* w2, const float* w3, const float* w4,
                              float* bufA, float* bufB, float* act, hipStream_t stream) {
    // conv1 7x7 s2: (n,3,128,128)->(n,64,64,64)
    conv7_bn_tiled<<<4*4*8*n, 256, 0, stream>>>(input, c1w, bng, bnb, bnm, bnv, bufA, n);
    // w1 3x3 s1: 64->128 @64x64
    conv3_tiled<1,16,16,16,8,512><<<4*4*8*n, 512, 0, stream>>>(bufA, w1, bufB, n, 64, 128, 64,64, 64,64);
    // w2 3x3 s2: 128->256, 64->32
    conv3_tiled<2,8,16,32,4,512><<<4*2*8*n, 512, 0, stream>>>(bufB, w2, bufA, n, 128, 256, 64,64, 32,32);
    // w3 3x3 s2: 256->512, 32->16
    conv3_tiled<2,8,16,32,4,512><<<2*1*16*n, 512, 0, stream>>>(bufA, w3, bufB, n, 256, 512, 32,32, 16,16);
    // w4 3x3 s2: 512->1024, 16->8
    conv3_tiled<2,8,8,64,4,512><<<1*1*16*n, 512, 0, stream>>>(bufB, w4, act, n, 512, 1024, 16,16, 8,8);
}

// ---------------- launcher ----------------
extern "C" void kernel_launch(void* const* d_in, const int* in_sizes, int n_in,
                              void* d_out_, int out_size, void* d_ws, size_t ws_size,
                              hipStream_t stream) {
    const float* x    = (const float*)d_in[0];
    const float* c1w  = (const float*)d_in[1];
    const float* bng  = (const float*)d_in[2];
    const float* bnb  = (const float*)d_in[3];
    const float* bnm  = (const float*)d_in[4];
    const float* bnv  = (const float*)d_in[5];
    const float* w1   = (const float*)d_in[6];
    const float* w2   = (const float*)d_in[7];
    const float* w3   = (const float*)d_in[8];
    const float* w4   = (const float*)d_in[9];
    const float* clsw = (const float*)d_in[10];
    const float* clsb = (const float*)d_in[11];
    float* dout = (float*)d_out_;
    float* ws   = (float*)d_ws;

    // output layout (f32 elements)
    float* out_gs = dout + 0;
    float* out_ls = dout + 160;
    float* out_cs = dout + 320;
    float* out_ws = dout + 2621760;
    float* out_hs = dout + 2642240;
    float* out_li = dout + 2662720;

    // Batched-local layout needs ~104.3 MiB of ws; fall back to 4x8 chunks otherwise.
    const size_t batched_floats = 27323328ull;
    const bool batched = ws_size >= batched_floats*4ull;

    float *bufA, *bufB, *act, *gmean, *gst, *cam, *xs, *ysn, *lmean, *locf;
    int *top, *box;
    if (batched) {
        bufA  = ws + 0;           // 8,388,608
        bufB  = ws + 8388608;     // 16,777,216
        act   = ws + 25165824;    // 2,097,152
        gmean = ws + 27262976;    // 8,192
        gst   = ws + 27271168;    // 160
        cam   = ws + 27271328;    // 10,240
        top   = (int*)(ws + 27281568);
        xs    = ws + 27281600;    // 4,096
        ysn   = ws + 27285696;    // 4,096
        box   = (int*)(ws + 27289792);
        lmean = ws + 27289920;    // 32,768
        locf  = ws + 27322688;    // 640
    } else {
        bufA  = ws + 0;           // 2,097,152
        bufB  = ws + 2097152;     // 4,194,304
        act   = ws + 6291456;     // 524,288
        gmean = ws + 6815744;
        gst   = ws + 6823936;
        cam   = ws + 6824096;
        top   = (int*)(ws + 6834336);
        xs    = ws + 6834368;
        ysn   = ws + 6838464;
        box   = (int*)(ws + 6842560);
        lmean = ws + 6842688;
        locf  = ws + 6875456;
    }

    // ---- global branch (8 images) ----
    run_feature_stack(x, 8, c1w, bng, bnb, bnm, bnv, w1, w2, w3, w4, bufA, bufB, act, stream);
    spatial_mean<<<32,256,0,stream>>>(act, gmean, 8192, 64);
    head_sigmoid<<<1,256,0,stream>>>(gmean, clsw, clsb, gst, out_gs, 8);
    cam_kernel<<<40,256,0,stream>>>(act, clsw, clsb, cam, 8);
    resize_cam<<<10240,256,0,stream>>>(cam, out_cs, 8);
    score_maxred<<<160,256,0,stream>>>(out_cs, out_ws, out_hs, 8);
    topk4<<<1,64,0,stream>>>(gst, top, 8);
    gather_norm<<<64,128,0,stream>>>(out_ws, out_hs, top, xs, ysn, 8);
    objloc<<<1,64,0,stream>>>(xs, ysn, box, 8);
    crop_resize_k<<<6144,256,0,stream>>>(x, box, out_li, 8);

    // ---- local branch ----
    if (batched) {
        run_feature_stack(out_li, 32, c1w, bng, bnb, bnm, bnv, w1, w2, w3, w4, bufA, bufB, act, stream);
        spatial_mean<<<128,256,0,stream>>>(act, lmean, 32768, 64);
    } else {
        for (int c = 0; c < 4; ++c) {
            const float* lin_c = out_li + (size_t)c*8*3*16384;
            run_feature_stack(lin_c, 8, c1w, bng, bnb, bnm, bnv, w1, w2, w3, w4, bufA, bufB, act, stream);
            spatial_mean<<<32,256,0,stream>>>(act, lmean + c*8192, 8192, 64);
        }
    }
    head_sigmoid<<<3,256,0,stream>>>(lmean, clsw, clsb, locf, (float*)nullptr, 32);
    local_stream_max<<<1,256,0,stream>>>(locf, out_ls, 8);
}

// Round 5
// 2930.620 us; speedup vs baseline: 9.7601x; 1.2615x over previous
//
#include <hip/hip_runtime.h>
#include <hip/hip_bf16.h>

// ---------------- helpers ----------------
__device__ __forceinline__ int sgnf(float v){ return (v>0.f)-(v<0.f); }

// =====================================================================
// Tiled 3x3 conv + relu, spill-free inner loop.
// in:(N,Ci,Hi,Wi) f32, w:(Co,Ci,3,3), out:(N,Co,Ho,Wo), pad=1
// Each thread: 2x4 output sub-tile for one co.
// =====================================================================
template<int STRIDE, int TH, int TW, int CO_T, int CI_T, int NT, int P>
__global__ __launch_bounds__(NT) void conv3_tiled(
    const float* __restrict__ in, const float* __restrict__ w, float* __restrict__ out,
    int N, int Ci, int Co, int Hi, int Wi, int Ho, int Wo)
{
    constexpr int NSP   = (TH/2)*(TW/4);
    constexpr int IT_H  = (TH-1)*STRIDE + 3;
    constexpr int IT_W  = (TW-1)*STRIDE + 3;
    constexpr int IN_ELEMS = CI_T*IT_H*IT_W;
    constexpr int W_ELEMS  = CI_T*CO_T*9;
    static_assert(NSP*CO_T == NT, "thread count mismatch");
    static_assert(IT_W <= P, "pitch too small");

    __shared__ __align__(16) float s_in[CI_T*IT_H*P];
    __shared__ __align__(16) float s_w[CI_T*CO_T*12];

    int bx = blockIdx.x;
    const int spxn = Wo/TW, spyn = Ho/TH, cog = Co/CO_T;
    const int sxb = bx % spxn; bx /= spxn;
    const int syb = bx % spyn; bx /= spyn;
    const int cg  = bx % cog;  const int n = bx / cog;
    const int tx0 = sxb*TW, ty0 = syb*TH, co0 = cg*CO_T;

    const int tid = threadIdx.x;
    const int sp  = tid % NSP;
    const int co  = tid / NSP;
    const int sy  = (sp / (TW/4)) * 2;
    const int sx  = (sp % (TW/4)) * 4;

    const int y_in0 = ty0*STRIDE - 1, x_in0 = tx0*STRIDE - 1;
    const float* in_n = in + (size_t)n*Ci*Hi*Wi;

    float acc[2][4] = {{0.f,0.f,0.f,0.f},{0.f,0.f,0.f,0.f}};

    for (int ci0 = 0; ci0 < Ci; ci0 += CI_T) {
        // ---- stage input tile (coalesced global reads, linear ds writes) ----
        for (int idx = tid; idx < IN_ELEMS; idx += NT) {
            int ci  = idx / (IT_H*IT_W);
            int rem = idx - ci*(IT_H*IT_W);
            int iy  = rem / IT_W;
            int ix  = rem - iy*IT_W;
            int gy = y_in0 + iy, gx = x_in0 + ix;
            float v = 0.f;
            if ((unsigned)gy < (unsigned)Hi && (unsigned)gx < (unsigned)Wi)
                v = in_n[(size_t)(ci0+ci)*Hi*Wi + gy*Wi + gx];
            s_in[ci*(IT_H*P) + iy*P + ix] = v;
        }
        // ---- stage weights ----
        for (int idx = tid; idx < W_ELEMS; idx += NT) {
            int ci  = idx / (CO_T*9);
            int rem = idx - ci*(CO_T*9);
            int c   = rem / 9, k = rem - c*9;
            s_w[(ci*CO_T + c)*12 + k] = w[((size_t)(co0+c)*Ci + (ci0+ci))*9 + k];
        }
        __syncthreads();

        #pragma unroll
        for (int ci = 0; ci < CI_T; ++ci) {
            const float* wp = &s_w[(ci*CO_T + co)*12];
            float4 wa = *(const float4*)wp;
            float4 wb = *(const float4*)(wp+4);
            float w8  = wp[8];
            float wr[9] = {wa.x,wa.y,wa.z,wa.w, wb.x,wb.y,wb.z,wb.w, w8};
            const float* ip = &s_in[ci*(IT_H*P)];

            if constexpr (STRIDE == 1) {
                // physical rows pr = 0..3 relative to sy; (ry,ky): ry+ky==pr
                #pragma unroll
                for (int pr = 0; pr < 4; ++pr) {
                    const float* row = ip + (sy+pr)*P + sx;
                    float4 a = *(const float4*)row;
                    float2 b = *(const float2*)(row+4);
                    float e[6] = {a.x,a.y,a.z,a.w,b.x,b.y};
                    #pragma unroll
                    for (int ky = 0; ky < 3; ++ky) {
                        constexpr int dummy = 0; (void)dummy;
                        int ry = pr - ky;
                        if (ry == 0 || ry == 1) {
                            #pragma unroll
                            for (int kx = 0; kx < 3; ++kx)
                                #pragma unroll
                                for (int rx = 0; rx < 4; ++rx)
                                    acc[ry][rx] += e[rx+kx] * wr[ky*3+kx];
                        }
                    }
                }
            } else {
                // physical rows pr = 0..4 relative to 2*sy; (ry,ky): 2*ry+ky==pr
                #pragma unroll
                for (int pr = 0; pr < 5; ++pr) {
                    const float* row = ip + (2*sy+pr)*P + 2*sx;
                    float4 a = *(const float4*)row;
                    float4 b = *(const float4*)(row+4);
                    float c8 = row[8];
                    float e[9] = {a.x,a.y,a.z,a.w,b.x,b.y,b.z,b.w,c8};
                    #pragma unroll
                    for (int ky = 0; ky < 3; ++ky) {
                        int ry2 = pr - ky;
                        if (ry2 == 0 || ry2 == 2) {
                            int ry = ry2 >> 1;
                            #pragma unroll
                            for (int kx = 0; kx < 3; ++kx)
                                #pragma unroll
                                for (int rx = 0; rx < 4; ++rx)
                                    acc[ry][rx] += e[2*rx+kx] * wr[ky*3+kx];
                        }
                    }
                }
            }
        }
        __syncthreads();
    }

    // ---- epilogue: relu + store ----
    float* op = out + ((size_t)n*Co + co0 + co)*Ho*Wo + (size_t)(ty0+sy)*Wo + (tx0+sx);
    #pragma unroll
    for (int ry=0; ry<2; ++ry) {
        float4 v;
        v.x = fmaxf(acc[ry][0], 0.f); v.y = fmaxf(acc[ry][1], 0.f);
        v.z = fmaxf(acc[ry][2], 0.f); v.w = fmaxf(acc[ry][3], 0.f);
        *(float4*)(op + (size_t)ry*Wo) = v;
    }
}

// =====================================================================
// Tiled 7x7 s2 p3 conv + BN, spill-free. x:(N,3,128,128)->(N,64,64,64)
// =====================================================================
__global__ __launch_bounds__(256) void conv7_bn_tiled(
    const float* __restrict__ x, const float* __restrict__ w,
    const float* __restrict__ gamma, const float* __restrict__ beta,
    const float* __restrict__ mean, const float* __restrict__ var,
    float* __restrict__ out, int N)
{
    constexpr int TH=16, TW=16, CO_T=8, NT=256, NSP=32;
    constexpr int IT = 37;                    // (16-1)*2+7
    constexpr int P  = 38;
    constexpr int IN_ELEMS = 3*IT*IT;
    constexpr int W_ELEMS  = CO_T*3*49;

    __shared__ __align__(16) float s_in[3*IT*P];
    __shared__ __align__(16) float s_w[CO_T*3*7*8];

    int bx = blockIdx.x;
    const int spn = 4, cog = 8;
    const int sxb = bx % spn; bx /= spn;
    const int syb = bx % spn; bx /= spn;
    const int cg  = bx % cog; const int n = bx / cog;
    const int tx0 = sxb*TW, ty0 = syb*TH, co0 = cg*CO_T;

    const int tid = threadIdx.x;
    const int sp  = tid % NSP;
    const int co  = tid / NSP;
    const int sy  = (sp / 4) * 2;
    const int sx  = (sp % 4) * 4;

    const int y_in0 = ty0*2 - 3, x_in0 = tx0*2 - 3;
    const float* x_n = x + (size_t)n*3*16384;

    for (int idx = tid; idx < IN_ELEMS; idx += NT) {
        int ci  = idx / (IT*IT);
        int rem = idx - ci*(IT*IT);
        int iy  = rem / IT;
        int ix  = rem - iy*IT;
        int gy = y_in0 + iy, gx = x_in0 + ix;
        float v = 0.f;
        if ((unsigned)gy < 128u && (unsigned)gx < 128u)
            v = x_n[(size_t)ci*16384 + gy*128 + gx];
        s_in[ci*(IT*P) + iy*P + ix] = v;
    }
    for (int idx = tid; idx < W_ELEMS; idx += NT) {
        int c   = idx / 147;
        int rem = idx - c*147;
        int ci  = rem / 49;
        int rem2= rem - ci*49;
        int ky  = rem2 / 7, kx = rem2 - ky*7;
        s_w[((c*3 + ci)*7 + ky)*8 + kx] = w[(size_t)(co0+c)*147 + ci*49 + ky*7 + kx];
    }
    __syncthreads();

    float acc[2][4] = {{0.f,0.f,0.f,0.f},{0.f,0.f,0.f,0.f}};
    const int c0 = 2*sx;
    #pragma unroll 1
    for (int ci = 0; ci < 3; ++ci) {
        const float* ip = &s_in[ci*(IT*P)];
        // physical rows pr = 0..8 relative to 2*sy; contributions 2*ry+ky == pr
        #pragma unroll
        for (int pr = 0; pr < 9; ++pr) {
            const float* row = ip + (2*sy+pr)*P + c0;
            float2 q0 = *(const float2*)(row+0);
            float2 q1 = *(const float2*)(row+2);
            float2 q2 = *(const float2*)(row+4);
            float2 q3 = *(const float2*)(row+6);
            float2 q4 = *(const float2*)(row+8);
            float2 q5 = *(const float2*)(row+10);
            float  e12 = row[12];
            float e[13] = {q0.x,q0.y,q1.x,q1.y,q2.x,q2.y,q3.x,q3.y,q4.x,q4.y,q5.x,q5.y,e12};
            #pragma unroll
            for (int ry = 0; ry < 2; ++ry) {
                int ky = pr - 2*ry;
                if (ky >= 0 && ky < 7) {
                    const float* wrow = &s_w[((co*3 + ci)*7 + ky)*8];
                    float4 wa = *(const float4*)wrow;
                    float2 wbv = *(const float2*)(wrow+4);
                    float w6 = wrow[6];
                    float wk[7] = {wa.x,wa.y,wa.z,wa.w,wbv.x,wbv.y,w6};
                    #pragma unroll
                    for (int kx = 0; kx < 7; ++kx)
                        #pragma unroll
                        for (int rx = 0; rx < 4; ++rx)
                            acc[ry][rx] += e[2*rx+kx] * wk[kx];
                }
            }
        }
    }

    const int coo = co0 + co;
    float inv = gamma[coo] / sqrtf(var[coo] + 1e-5f);
    float mu = mean[coo], bb = beta[coo];
    float* op = out + ((size_t)n*64 + coo)*4096 + (size_t)(ty0+sy)*64 + (tx0+sx);
    #pragma unroll
    for (int ry=0; ry<2; ++ry) {
        float4 v;
        v.x = (acc[ry][0]-mu)*inv + bb; v.y = (acc[ry][1]-mu)*inv + bb;
        v.z = (acc[ry][2]-mu)*inv + bb; v.w = (acc[ry][3]-mu)*inv + bb;
        *(float4*)(op + (size_t)ry*64) = v;
    }
}

// ---------------- spatial mean over HW ----------------
__global__ void spatial_mean(const float* __restrict__ in, float* __restrict__ out,
                             int rows, int HW) {
    int idx = blockIdx.x*blockDim.x + threadIdx.x;
    if (idx >= rows) return;
    const float* p = in + (size_t)idx*HW;
    float s = 0.f;
    for (int i=0;i<HW;++i) s += p[i];
    out[idx] = s / (float)HW;
}

// ---------------- classifier head ----------------
__global__ void head_sigmoid(const float* __restrict__ m, const float* __restrict__ cw,
                             const float* __restrict__ cb, float* __restrict__ out0,
                             float* __restrict__ out1, int Nrows) {
    int idx = blockIdx.x*blockDim.x + threadIdx.x;
    if (idx >= Nrows*20) return;
    int o = idx % 20, n = idx / 20;
    const float* mp = m + (size_t)n*1024;
    const float* wp = cw + (size_t)o*1024;
    float s = cb[o];
    for (int c=0;c<1024;++c) s += mp[c]*wp[c];
    float v = 1.f/(1.f+expf(-s));
    out0[idx] = v;
    if (out1) out1[idx] = v;
}

// ---------------- cam ----------------
__global__ void cam_kernel(const float* __restrict__ act, const float* __restrict__ cw,
                           const float* __restrict__ cb, float* __restrict__ cam, int N) {
    int idx = blockIdx.x*blockDim.x + threadIdx.x;
    if (idx >= N*20*64) return;
    int p = idx & 63; int o = (idx>>6) % 20; int n = idx / 1280;
    const float* a = act + (size_t)n*1024*64 + p;
    const float* wp = cw + (size_t)o*1024;
    float s = cb[o];
    for (int c=0;c<1024;++c) s += a[c*64]*wp[c];
    cam[idx] = 1.f/(1.f+expf(-s));
}

// ---------------- bilinear resize cam ----------------
__global__ void resize_cam(const float* __restrict__ cam, float* __restrict__ cs, int N) {
    int idx = blockIdx.x*blockDim.x + threadIdx.x;
    if (idx >= N*20*16384) return;
    int xo = idx & 127, yo = (idx>>7)&127;
    int bo = idx >> 14;
    float fy = (float)yo * (7.0f/127.0f);
    float fx = (float)xo * (7.0f/127.0f);
    int y0 = (int)floorf(fy); float wy = fy - (float)y0;
    int x0 = (int)floorf(fx); float wx = fx - (float)x0;
    if (y0 > 7) y0 = 7; if (y0 < 0) y0 = 0; int y1 = min(y0+1, 7);
    if (x0 > 7) x0 = 7; if (x0 < 0) x0 = 0; int x1 = min(x0+1, 7);
    const float* c = cam + (size_t)bo*64;
    float v = (1.f-wy)*((1.f-wx)*c[y0*8+x0] + wx*c[y0*8+x1])
            +      wy *((1.f-wx)*c[y1*8+x0] + wx*c[y1*8+x1]);
    cs[idx] = v;
}

// ---------------- wscore / hscore max reductions ----------------
__global__ void score_maxred(const float* __restrict__ cs, float* __restrict__ wsc,
                             float* __restrict__ hsc, int N) {
    int idx = blockIdx.x*blockDim.x + threadIdx.x;
    int total = N*20*128;
    if (idx >= 2*total) return;
    if (idx < total) {
        int wcol = idx % 128; int bo = idx / 128;
        const float* p = cs + (size_t)bo*16384 + wcol;
        float mv = -1e30f;
        for (int h=0; h<128; ++h) mv = fmaxf(mv, p[h*128]);
        wsc[idx] = mv;
    } else {
        int i = idx - total;
        int hrow = i % 128; int bo = i / 128;
        const float* p = cs + (size_t)bo*16384 + hrow*128;
        float mv = -1e30f;
        for (int w_=0; w_<128; ++w_) mv = fmaxf(mv, p[w_]);
        hsc[i] = mv;
    }
}

// ---------------- stable top-4 of 20 per batch ----------------
__global__ void topk4(const float* __restrict__ gs, int* __restrict__ top, int N) {
    int n = threadIdx.x;
    if (n >= N) return;
    const float* g = gs + n*20;
    bool used[20];
    for (int i=0;i<20;++i) used[i]=false;
    for (int t=0;t<4;++t) {
        int bi = -1; float bv = -1e30f;
        for (int i=0;i<20;++i) {
            if (!used[i] && g[i] > bv) { bv = g[i]; bi = i; }
        }
        used[bi] = true;
        top[n*4+t] = bi;
    }
}

// ---------------- gather top rows + norm01 ----------------
__global__ void gather_norm(const float* __restrict__ wsc, const float* __restrict__ hsc,
                            const int* __restrict__ top, float* __restrict__ xs,
                            float* __restrict__ ysn, int N) {
    int r = blockIdx.x;
    int axis = r / (N*4); int row = r % (N*4);
    int b = row / 4;
    int cls = top[row];
    const float* src = (axis==0 ? wsc : hsc) + ((size_t)b*20 + cls)*128;
    int t = threadIdx.x;
    float v = src[t];
    __shared__ float smn[128], smx[128];
    smn[t] = v; smx[t] = v;
    __syncthreads();
    for (int off=64; off>0; off>>=1) {
        if (t < off) { smn[t] = fminf(smn[t], smn[t+off]); smx[t] = fmaxf(smx[t], smx[t+off]); }
        __syncthreads();
    }
    float mn = smn[0], mx = smx[0];
    float outv;
    if (mx == mn) outv = v / (mx == 0.f ? 1.f : mx);
    else          outv = (v - mn) / (mx - mn);
    (axis==0 ? xs : ysn)[row*128 + t] = outv;
}

// ---------------- obj_loc ----------------
__global__ void objloc(const float* __restrict__ xs, const float* __restrict__ ysn,
                       int* __restrict__ box, int N) {
    int i = threadIdx.x;
    if (i >= 2*N*4) return;
    int axis = i / (N*4); int row = i % (N*4);
    const float* s = (axis ? ysn : xs) + (size_t)row*128;
    const int S = 128, minsize = 16;
    int pos[127]; int ncross = 0;
    int prev = sgnf(s[0] - 0.5f);
    for (int k=1; k<S; ++k) {
        int cur = sgnf(s[k] - 0.5f);
        int d = cur - prev; if (d < 0) d = -d;
        if (d == 2) pos[ncross++] = k-1;
        prev = cur;
    }
    float m = -1e30f;
    for (int k=0; k<S; ++k) m = fmaxf(m, s[k]);
    int zmin = 0, zmax = S, bestkey = -2;
    int a = 0;
    for (int j=0; j<=ncross; ++j) {
        int bnd = (j < ncross) ? pos[j] : S;
        float sm = -1e30f;
        for (int k=a; k<bnd; ++k) sm = fmaxf(sm, s[k]);
        int len = bnd - a;
        int key = (sm == m) ? len : -1;
        if (key > bestkey) { bestkey = key; zmin = a; zmax = bnd; }
        a = bnd;
    }
    bool need = (zmax - zmin) <= minsize;
    int pad = minsize - (zmax - zmin);
    int cp = (pad + 1) >> 1;
    bool c1 = need && (zmin > cp) && (S - zmax > pad);
    if (c1) { zmin = zmin - cp + 1; zmax = zmax + cp; }
    bool c2 = need && (zmin < cp);
    if (c2) { zmin = 0; zmax = minsize; }
    bool c3 = need && (S - zmax < cp);
    if (c3) { zmin = S - minsize + 1; zmax = S; }
    if (ncross == 0) { zmin = minsize; zmax = 112; }
    if (axis == 0) { box[row] = zmin; box[32+row] = zmax; }
    else           { box[64+row] = zmin; box[96+row] = zmax; }
}

// ---------------- crop + bilinear resize ----------------
__global__ void crop_resize_k(const float* __restrict__ x, const int* __restrict__ box,
                              float* __restrict__ lin, int N) {
    int idx = blockIdx.x*blockDim.x + threadIdx.x;
    if (idx >= N*4*3*16384) return;
    int xo = idx & 127, yo = (idx>>7)&127;
    int c  = (idx>>14) % 3;
    int r  = idx / 49152;
    int b  = r / 4;
    int cx1 = box[r],    cx2 = box[32+r];
    int cy1 = box[64+r], cy2 = box[96+r];
    float fy = (float)cy1 + (float)(yo * (cy2 - 1 - cy1)) / 127.0f;
    float fx = (float)cx1 + (float)(xo * (cx2 - 1 - cx1)) / 127.0f;
    float wy = fy - floorf(fy);
    float wx = fx - floorf(fx);
    int y0 = min(max((int)floorf(fy), 0), 127); int y1 = min(y0 + 1, 127);
    int x0 = min(max((int)floorf(fx), 0), 127); int x1 = min(x0 + 1, 127);
    const float* img = x + ((size_t)b*3 + c)*16384;
    float v = (1.f-wy)*((1.f-wx)*img[y0*128+x0] + wx*img[y0*128+x1])
            +      wy *((1.f-wx)*img[y1*128+x0] + wx*img[y1*128+x1]);
    lin[idx] = v;
}

// ---------------- local_stream = max over TOPN ----------------
__global__ void local_stream_max(const float* __restrict__ loc, float* __restrict__ out, int N) {
    int idx = threadIdx.x;
    if (idx >= N*20) return;
    int o = idx % 20, b = idx / 20;
    float mv = -1e30f;
    for (int t=0; t<4; ++t) mv = fmaxf(mv, loc[((size_t)(b*4+t))*20 + o]);
    out[idx] = mv;
}

// ---------------- conv stack helper ----------------
static void run_feature_stack(const float* input, int n,
                              const float* c1w, const float* bng, const float* bnb,
                              const float* bnm, const float* bnv,
                              const float* w1, const float* w2, const float* w3, const float* w4,
                              float* bufA, float* bufB, float* act, hipStream_t stream) {
    // conv1 7x7 s2: (n,3,128,128)->(n,64,64,64)
    conv7_bn_tiled<<<4*4*8*n, 256, 0, stream>>>(input, c1w, bng, bnb, bnm, bnv, bufA, n);
    // w1 3x3 s1: 64->128 @64x64    grid = (64/16)*(64/16)*(128/16)*n
    conv3_tiled<1,16,16,16,8,512,24><<<4*4*8*n, 512, 0, stream>>>(bufA, w1, bufB, n, 64, 128, 64,64, 64,64);
    // w2 3x3 s2: 128->256, 64->32  grid = (32/8)*(32/8)*(256/64)*n
    conv3_tiled<2,8,8,64,8,512,20><<<4*4*4*n, 512, 0, stream>>>(bufB, w2, bufA, n, 128, 256, 64,64, 32,32);
    // w3 3x3 s2: 256->512, 32->16  grid = (16/8)*(16/8)*(512/64)*n
    conv3_tiled<2,8,8,64,8,512,20><<<2*2*8*n, 512, 0, stream>>>(bufA, w3, bufB, n, 256, 512, 32,32, 16,16);
    // w4 3x3 s2: 512->1024, 16->8  grid = (8/8)*(8/8)*(1024/32)*n
    conv3_tiled<2,8,8,32,8,256,20><<<1*1*32*n, 256, 0, stream>>>(bufB, w4, act, n, 512, 1024, 16,16, 8,8);
}

// ---------------- launcher ----------------
extern "C" void kernel_launch(void* const* d_in, const int* in_sizes, int n_in,
                              void* d_out_, int out_size, void* d_ws, size_t ws_size,
                              hipStream_t stream) {
    const float* x    = (const float*)d_in[0];
    const float* c1w  = (const float*)d_in[1];
    const float* bng  = (const float*)d_in[2];
    const float* bnb  = (const float*)d_in[3];
    const float* bnm  = (const float*)d_in[4];
    const float* bnv  = (const float*)d_in[5];
    const float* w1   = (const float*)d_in[6];
    const float* w2   = (const float*)d_in[7];
    const float* w3   = (const float*)d_in[8];
    const float* w4   = (const float*)d_in[9];
    const float* clsw = (const float*)d_in[10];
    const float* clsb = (const float*)d_in[11];
    float* dout = (float*)d_out_;
    float* ws   = (float*)d_ws;

    // output layout (f32 elements)
    float* out_gs = dout + 0;
    float* out_ls = dout + 160;
    float* out_cs = dout + 320;
    float* out_ws = dout + 2621760;
    float* out_hs = dout + 2642240;
    float* out_li = dout + 2662720;

    // Batched-local layout needs ~104.3 MiB of ws; fall back to 4x8 chunks otherwise.
    const size_t batched_floats = 27323328ull;
    const bool batched = ws_size >= batched_floats*4ull;

    float *bufA, *bufB, *act, *gmean, *gst, *cam, *xs, *ysn, *lmean, *locf;
    int *top, *box;
    if (batched) {
        bufA  = ws + 0;
        bufB  = ws + 8388608;
        act   = ws + 25165824;
        gmean = ws + 27262976;
        gst   = ws + 27271168;
        cam   = ws + 27271328;
        top   = (int*)(ws + 27281568);
        xs    = ws + 27281600;
        ysn   = ws + 27285696;
        box   = (int*)(ws + 27289792);
        lmean = ws + 27289920;
        locf  = ws + 27322688;
    } else {
        bufA  = ws + 0;
        bufB  = ws + 2097152;
        act   = ws + 6291456;
        gmean = ws + 6815744;
        gst   = ws + 6823936;
        cam   = ws + 6824096;
        top   = (int*)(ws + 6834336);
        xs    = ws + 6834368;
        ysn   = ws + 6838464;
        box   = (int*)(ws + 6842560);
        lmean = ws + 6842688;
        locf  = ws + 6875456;
    }

    // ---- global branch (8 images) ----
    run_feature_stack(x, 8, c1w, bng, bnb, bnm, bnv, w1, w2, w3, w4, bufA, bufB, act, stream);
    spatial_mean<<<32,256,0,stream>>>(act, gmean, 8192, 64);
    head_sigmoid<<<1,256,0,stream>>>(gmean, clsw, clsb, gst, out_gs, 8);
    cam_kernel<<<40,256,0,stream>>>(act, clsw, clsb, cam, 8);
    resize_cam<<<10240,256,0,stream>>>(cam, out_cs, 8);
    score_maxred<<<160,256,0,stream>>>(out_cs, out_ws, out_hs, 8);
    topk4<<<1,64,0,stream>>>(gst, top, 8);
    gather_norm<<<64,128,0,stream>>>(out_ws, out_hs, top, xs, ysn, 8);
    objloc<<<1,64,0,stream>>>(xs, ysn, box, 8);
    crop_resize_k<<<6144,256,0,stream>>>(x, box, out_li, 8);

    // ---- local branch ----
    if (batched) {
        run_feature_stack(out_li, 32, c1w, bng, bnb, bnm, bnv, w1, w2, w3, w4, bufA, bufB, act, stream);
        spatial_mean<<<128,256,0,stream>>>(act, lmean, 32768, 64);
    } else {
        for (int c = 0; c < 4; ++c) {
            const float* lin_c = out_li + (size_t)c*8*3*16384;
            run_feature_stack(lin_c, 8, c1w, bng, bnb, bnm, bnv, w1, w2, w3, w4, bufA, bufB, act, stream);
            spatial_mean<<<32,256,0,stream>>>(act, lmean + c*8192, 8192, 64);
        }
    }
    head_sigmoid<<<3,256,0,stream>>>(lmean, clsw, clsb, locf, (float*)nullptr, 32);
    local_stream_max<<<1,256,0,stream>>>(locf, out_ls, 8);
}

// Round 6
// 2172.836 us; speedup vs baseline: 13.1640x; 1.3488x over previous
//
#include <hip/hip_runtime.h>
#include <hip/hip_bf16.h>

// ---------------- helpers ----------------
__device__ __forceinline__ int sgnf(float v){ return (v>0.f)-(v<0.f); }
__device__ __forceinline__ ushort f2b(float f){ __hip_bfloat16 h = __float2bfloat16(f); return __builtin_bit_cast(ushort, h); }
__device__ __forceinline__ float  b2f(ushort u){ __hip_bfloat16 h = __builtin_bit_cast(__hip_bfloat16, u); return __bfloat162float(h); }
__device__ __forceinline__ float  tof(float v){ return v; }
__device__ __forceinline__ float  tof(ushort v){ return b2f(v); }

typedef short  s8v  __attribute__((ext_vector_type(8)));
typedef ushort us8  __attribute__((ext_vector_type(8)));
typedef float  f4v  __attribute__((ext_vector_type(4)));

// =====================================================================
// f32 tiled 3x3 conv + relu (global branch + fallback). Unchanged math
// from round 5 (verified); only tile params differ at call sites.
// =====================================================================
template<int STRIDE, int TH, int TW, int CO_T, int CI_T, int NT, int P>
__global__ __launch_bounds__(NT) void conv3_tiled(
    const float* __restrict__ in, const float* __restrict__ w, float* __restrict__ out,
    int N, int Ci, int Co, int Hi, int Wi, int Ho, int Wo)
{
    constexpr int NSP   = (TH/2)*(TW/4);
    constexpr int IT_H  = (TH-1)*STRIDE + 3;
    constexpr int IT_W  = (TW-1)*STRIDE + 3;
    constexpr int IN_ELEMS = CI_T*IT_H*IT_W;
    constexpr int W_ELEMS  = CI_T*CO_T*9;
    static_assert(NSP*CO_T == NT, "thread count mismatch");
    static_assert(IT_W <= P, "pitch too small");

    __shared__ __align__(16) float s_in[CI_T*IT_H*P];
    __shared__ __align__(16) float s_w[CI_T*CO_T*12];

    int bx = blockIdx.x;
    const int spxn = Wo/TW, spyn = Ho/TH, cog = Co/CO_T;
    const int sxb = bx % spxn; bx /= spxn;
    const int syb = bx % spyn; bx /= spyn;
    const int cg  = bx % cog;  const int n = bx / cog;
    const int tx0 = sxb*TW, ty0 = syb*TH, co0 = cg*CO_T;

    const int tid = threadIdx.x;
    const int sp  = tid % NSP;
    const int co  = tid / NSP;
    const int sy  = (sp / (TW/4)) * 2;
    const int sx  = (sp % (TW/4)) * 4;

    const int y_in0 = ty0*STRIDE - 1, x_in0 = tx0*STRIDE - 1;
    const float* in_n = in + (size_t)n*Ci*Hi*Wi;

    float acc[2][4] = {{0.f,0.f,0.f,0.f},{0.f,0.f,0.f,0.f}};

    for (int ci0 = 0; ci0 < Ci; ci0 += CI_T) {
        for (int idx = tid; idx < IN_ELEMS; idx += NT) {
            int ci  = idx / (IT_H*IT_W);
            int rem = idx - ci*(IT_H*IT_W);
            int iy  = rem / IT_W;
            int ix  = rem - iy*IT_W;
            int gy = y_in0 + iy, gx = x_in0 + ix;
            float v = 0.f;
            if ((unsigned)gy < (unsigned)Hi && (unsigned)gx < (unsigned)Wi)
                v = in_n[(size_t)(ci0+ci)*Hi*Wi + gy*Wi + gx];
            s_in[ci*(IT_H*P) + iy*P + ix] = v;
        }
        for (int idx = tid; idx < W_ELEMS; idx += NT) {
            int ci  = idx / (CO_T*9);
            int rem = idx - ci*(CO_T*9);
            int c   = rem / 9, k = rem - c*9;
            s_w[(ci*CO_T + c)*12 + k] = w[((size_t)(co0+c)*Ci + (ci0+ci))*9 + k];
        }
        __syncthreads();

        #pragma unroll
        for (int ci = 0; ci < CI_T; ++ci) {
            const float* wp = &s_w[(ci*CO_T + co)*12];
            float4 wa = *(const float4*)wp;
            float4 wb = *(const float4*)(wp+4);
            float w8  = wp[8];
            float wr[9] = {wa.x,wa.y,wa.z,wa.w, wb.x,wb.y,wb.z,wb.w, w8};
            const float* ip = &s_in[ci*(IT_H*P)];

            if constexpr (STRIDE == 1) {
                #pragma unroll
                for (int pr = 0; pr < 4; ++pr) {
                    const float* row = ip + (sy+pr)*P + sx;
                    float4 a = *(const float4*)row;
                    float2 b = *(const float2*)(row+4);
                    float e[6] = {a.x,a.y,a.z,a.w,b.x,b.y};
                    #pragma unroll
                    for (int ky = 0; ky < 3; ++ky) {
                        int ry = pr - ky;
                        if (ry == 0 || ry == 1) {
                            #pragma unroll
                            for (int kx = 0; kx < 3; ++kx)
                                #pragma unroll
                                for (int rx = 0; rx < 4; ++rx)
                                    acc[ry][rx] += e[rx+kx] * wr[ky*3+kx];
                        }
                    }
                }
            } else {
                #pragma unroll
                for (int pr = 0; pr < 5; ++pr) {
                    const float* row = ip + (2*sy+pr)*P + 2*sx;
                    float4 a = *(const float4*)row;
                    float4 b = *(const float4*)(row+4);
                    float c8 = row[8];
                    float e[9] = {a.x,a.y,a.z,a.w,b.x,b.y,b.z,b.w,c8};
                    #pragma unroll
                    for (int ky = 0; ky < 3; ++ky) {
                        int ry2 = pr - ky;
                        if (ry2 == 0 || ry2 == 2) {
                            int ry = ry2 >> 1;
                            #pragma unroll
                            for (int kx = 0; kx < 3; ++kx)
                                #pragma unroll
                                for (int rx = 0; rx < 4; ++rx)
                                    acc[ry][rx] += e[2*rx+kx] * wr[ky*3+kx];
                        }
                    }
                }
            }
        }
        __syncthreads();
    }

    float* op = out + ((size_t)n*Co + co0 + co)*Ho*Wo + (size_t)(ty0+sy)*Wo + (tx0+sx);
    #pragma unroll
    for (int ry=0; ry<2; ++ry) {
        float4 v;
        v.x = fmaxf(acc[ry][0], 0.f); v.y = fmaxf(acc[ry][1], 0.f);
        v.z = fmaxf(acc[ry][2], 0.f); v.w = fmaxf(acc[ry][3], 0.f);
        *(float4*)(op + (size_t)ry*Wo) = v;
    }
}

// =====================================================================
// 7x7 s2 p3 conv + BN (f32 math). TO = float (global) or ushort bf16 (local)
// =====================================================================
template<typename TO>
__global__ __launch_bounds__(256) void conv7_bn_tiled(
    const float* __restrict__ x, const float* __restrict__ w,
    const float* __restrict__ gamma, const float* __restrict__ beta,
    const float* __restrict__ mean, const float* __restrict__ var,
    TO* __restrict__ out, int N)
{
    constexpr int TH=16, TW=16, CO_T=8, NT=256, NSP=32;
    constexpr int IT = 37;
    constexpr int P  = 38;
    constexpr int IN_ELEMS = 3*IT*IT;
    constexpr int W_ELEMS  = CO_T*3*49;

    __shared__ __align__(16) float s_in[3*IT*P];
    __shared__ __align__(16) float s_w[CO_T*3*7*8];

    int bx = blockIdx.x;
    const int spn = 4, cog = 8;
    const int sxb = bx % spn; bx /= spn;
    const int syb = bx % spn; bx /= spn;
    const int cg  = bx % cog; const int n = bx / cog;
    const int tx0 = sxb*TW, ty0 = syb*TH, co0 = cg*CO_T;

    const int tid = threadIdx.x;
    const int sp  = tid % NSP;
    const int co  = tid / NSP;
    const int sy  = (sp / 4) * 2;
    const int sx  = (sp % 4) * 4;

    const int y_in0 = ty0*2 - 3, x_in0 = tx0*2 - 3;
    const float* x_n = x + (size_t)n*3*16384;

    for (int idx = tid; idx < IN_ELEMS; idx += NT) {
        int ci  = idx / (IT*IT);
        int rem = idx - ci*(IT*IT);
        int iy  = rem / IT;
        int ix  = rem - iy*IT;
        int gy = y_in0 + iy, gx = x_in0 + ix;
        float v = 0.f;
        if ((unsigned)gy < 128u && (unsigned)gx < 128u)
            v = x_n[(size_t)ci*16384 + gy*128 + gx];
        s_in[ci*(IT*P) + iy*P + ix] = v;
    }
    for (int idx = tid; idx < W_ELEMS; idx += NT) {
        int c   = idx / 147;
        int rem = idx - c*147;
        int ci  = rem / 49;
        int rem2= rem - ci*49;
        int ky  = rem2 / 7, kx = rem2 - ky*7;
        s_w[((c*3 + ci)*7 + ky)*8 + kx] = w[(size_t)(co0+c)*147 + ci*49 + ky*7 + kx];
    }
    __syncthreads();

    float acc[2][4] = {{0.f,0.f,0.f,0.f},{0.f,0.f,0.f,0.f}};
    const int c0 = 2*sx;
    #pragma unroll 1
    for (int ci = 0; ci < 3; ++ci) {
        const float* ip = &s_in[ci*(IT*P)];
        #pragma unroll
        for (int pr = 0; pr < 9; ++pr) {
            const float* row = ip + (2*sy+pr)*P + c0;
            float2 q0 = *(const float2*)(row+0);
            float2 q1 = *(const float2*)(row+2);
            float2 q2 = *(const float2*)(row+4);
            float2 q3 = *(const float2*)(row+6);
            float2 q4 = *(const float2*)(row+8);
            float2 q5 = *(const float2*)(row+10);
            float  e12 = row[12];
            float e[13] = {q0.x,q0.y,q1.x,q1.y,q2.x,q2.y,q3.x,q3.y,q4.x,q4.y,q5.x,q5.y,e12};
            #pragma unroll
            for (int ry = 0; ry < 2; ++ry) {
                int ky = pr - 2*ry;
                if (ky >= 0 && ky < 7) {
                    const float* wrow = &s_w[((co*3 + ci)*7 + ky)*8];
                    float4 wa = *(const float4*)wrow;
                    float2 wbv = *(const float2*)(wrow+4);
                    float w6 = wrow[6];
                    float wk[7] = {wa.x,wa.y,wa.z,wa.w,wbv.x,wbv.y,w6};
                    #pragma unroll
                    for (int kx = 0; kx < 7; ++kx)
                        #pragma unroll
                        for (int rx = 0; rx < 4; ++rx)
                            acc[ry][rx] += e[2*rx+kx] * wk[kx];
                }
            }
        }
    }

    const int coo = co0 + co;
    float inv = gamma[coo] / sqrtf(var[coo] + 1e-5f);
    float mu = mean[coo], bb = beta[coo];
    TO* op = out + ((size_t)n*64 + coo)*4096 + (size_t)(ty0+sy)*64 + (tx0+sx);
    #pragma unroll
    for (int ry=0; ry<2; ++ry) {
        float v0 = (acc[ry][0]-mu)*inv + bb; float v1 = (acc[ry][1]-mu)*inv + bb;
        float v2 = (acc[ry][2]-mu)*inv + bb; float v3 = (acc[ry][3]-mu)*inv + bb;
        if constexpr (sizeof(TO) == 4) {
            float4 v; v.x=v0; v.y=v1; v.z=v2; v.w=v3;
            *(float4*)((float*)op + (size_t)ry*64) = v;
        } else {
            ushort4 u; u.x=f2b(v0); u.y=f2b(v1); u.z=f2b(v2); u.w=f2b(v3);
            *(ushort4*)((ushort*)op + (size_t)ry*64) = u;
        }
    }
}

// =====================================================================
// weight f32 -> bf16 cast (layout preserved: [Co][Ci*9] IS the GEMM A)
// =====================================================================
__global__ void wcast(const float* __restrict__ src, ushort* __restrict__ dst, int n) {
    int i = blockIdx.x*blockDim.x + threadIdx.x;
    if (i < n) dst[i] = f2b(src[i]);
}

// =====================================================================
// im2row: bf16 NCHW activations -> Brow[p][k] (k = ci*9 + ky*3 + kx)
// lanes walk k => fully coalesced 16B row-segment writes.
// =====================================================================
__global__ void im2row_k(const ushort* __restrict__ in, ushort* __restrict__ Brow,
                         int n0, int NN, int Ci, int Hi, int Wi, int Ho, int Wo,
                         int stride, int K) {
    int idx = blockIdx.x*blockDim.x + threadIdx.x;
    int K8 = K >> 3;
    if (idx >= NN * K8) return;
    int ks = idx % K8;
    int p  = idx / K8;
    int xo = p % Wo; int t = p / Wo; int yo = t % Ho; int nl = t / Ho;
    const ushort* ip = in + (size_t)(n0 + nl)*Ci*Hi*Wi;
    int y0 = yo*stride - 1, x0 = xo*stride - 1;
    us8 v;
    #pragma unroll
    for (int j = 0; j < 8; ++j) {
        int k = ks*8 + j;
        int ci = k / 9, tt = k - ci*9;
        int ky = tt / 3, kx = tt - ky*3;
        int yi = y0 + ky, xi = x0 + kx;
        ushort val = 0;
        if ((unsigned)yi < (unsigned)Hi && (unsigned)xi < (unsigned)Wi)
            val = ip[(size_t)ci*Hi*Wi + yi*Wi + xi];
        v[j] = val;
    }
    *(us8*)&Brow[(size_t)p*K + ks*8] = v;
}

// =====================================================================
// bf16 MFMA GEMM: C[M][NN] = relu(A[M][K] * Brow[NN][K]^T), out NCHW bf16.
// Block tile 64(M) x 128(N), 4 waves (2x2), 16x16x32 bf16 MFMA.
// LDS XOR-swizzle: phys_chunk = chunk ^ ((row>>1)&3)  (16B aligned, ~2-way)
// =====================================================================
__global__ __launch_bounds__(256) void gemm_conv(
    const ushort* __restrict__ A, const ushort* __restrict__ B,
    ushort* __restrict__ out,
    int M, int K, int NN, int Co, int hwShift, int n0)
{
    __shared__ __align__(16) ushort sA[64*32];
    __shared__ __align__(16) ushort sB[128*32];

    int bx = blockIdx.x;
    int mtiles = M >> 6;
    int mt = bx % mtiles;
    int nt = bx / mtiles;
    int co0 = mt << 6, p0 = nt << 7;
    int tid = threadIdx.x, lane = tid & 63, wave = tid >> 6;
    int wm = wave & 1, wn = wave >> 1;

    f4v acc[2][4];
    #pragma unroll
    for (int i=0;i<2;++i)
        #pragma unroll
        for (int j=0;j<4;++j)
            #pragma unroll
            for (int r=0;r<4;++r) acc[i][j][r] = 0.f;

    const int g  = lane >> 4;
    const int li = lane & 15;

    for (int k0 = 0; k0 < K; k0 += 32) {
        {   // stage A: 64 rows x 4 segs
            int r = tid >> 2, s = tid & 3;
            int sp = s ^ ((r >> 1) & 3);
            us8 val = *(const us8*)&A[(size_t)(co0 + r)*K + k0 + s*8];
            *(us8*)&sA[r*32 + sp*8] = val;
        }
        #pragma unroll
        for (int h = 0; h < 2; ++h) {   // stage B: 128 rows x 4 segs
            int slot = tid + h*256;
            int r = slot >> 2, s = slot & 3;
            int sp = s ^ ((r >> 1) & 3);
            us8 val = *(const us8*)&B[(size_t)(p0 + r)*K + k0 + s*8];
            *(us8*)&sB[r*32 + sp*8] = val;
        }
        __syncthreads();

        s8v a0, a1, b0, b1, b2, b3;
        {
            int r = wm*32 + li;
            a0 = *(const s8v*)&sA[r*32 + ((g ^ ((r>>1)&3)))*8];
            int r2 = r + 16;
            a1 = *(const s8v*)&sA[r2*32 + ((g ^ ((r2>>1)&3)))*8];
        }
        {
            int r = wn*64 + li;
            b0 = *(const s8v*)&sB[r*32 + ((g ^ ((r>>1)&3)))*8];
            int r1 = r + 16;
            b1 = *(const s8v*)&sB[r1*32 + ((g ^ ((r1>>1)&3)))*8];
            int r2 = r + 32;
            b2 = *(const s8v*)&sB[r2*32 + ((g ^ ((r2>>1)&3)))*8];
            int r3 = r + 48;
            b3 = *(const s8v*)&sB[r3*32 + ((g ^ ((r3>>1)&3)))*8];
        }
        acc[0][0] = __builtin_amdgcn_mfma_f32_16x16x32_bf16(a0, b0, acc[0][0], 0, 0, 0);
        acc[0][1] = __builtin_amdgcn_mfma_f32_16x16x32_bf16(a0, b1, acc[0][1], 0, 0, 0);
        acc[0][2] = __builtin_amdgcn_mfma_f32_16x16x32_bf16(a0, b2, acc[0][2], 0, 0, 0);
        acc[0][3] = __builtin_amdgcn_mfma_f32_16x16x32_bf16(a0, b3, acc[0][3], 0, 0, 0);
        acc[1][0] = __builtin_amdgcn_mfma_f32_16x16x32_bf16(a1, b0, acc[1][0], 0, 0, 0);
        acc[1][1] = __builtin_amdgcn_mfma_f32_16x16x32_bf16(a1, b1, acc[1][1], 0, 0, 0);
        acc[1][2] = __builtin_amdgcn_mfma_f32_16x16x32_bf16(a1, b2, acc[1][2], 0, 0, 0);
        acc[1][3] = __builtin_amdgcn_mfma_f32_16x16x32_bf16(a1, b3, acc[1][3], 0, 0, 0);
        __syncthreads();
    }

    int hwMask = (1 << hwShift) - 1;
    #pragma unroll
    for (int i = 0; i < 2; ++i) {
        #pragma unroll
        for (int j = 0; j < 4; ++j) {
            #pragma unroll
            for (int r = 0; r < 4; ++r) {
                int co = co0 + wm*32 + i*16 + g*4 + r;
                int p  = p0 + wn*64 + j*16 + li;
                int nimg = p >> hwShift, sphw = p & hwMask;
                float v = fmaxf(acc[i][j][r], 0.f);
                out[(((size_t)(n0 + nimg)*Co + co) << hwShift) + sphw] = f2b(v);
            }
        }
    }
}

// ---------------- per-row (64-elem) mean via wave reduce ----------------
template<typename T>
__global__ void row_mean64(const T* __restrict__ in, float* __restrict__ out, int rows) {
    int w = (blockIdx.x*blockDim.x + threadIdx.x) >> 6;
    int lane = threadIdx.x & 63;
    if (w >= rows) return;
    float v = tof(in[(size_t)w*64 + lane]);
    #pragma unroll
    for (int off = 32; off > 0; off >>= 1) v += __shfl_down(v, off, 64);
    if (lane == 0) out[w] = v * (1.f/64.f);
}

// ---------------- classifier head ----------------
__global__ void head_sigmoid(const float* __restrict__ m, const float* __restrict__ cw,
                             const float* __restrict__ cb, float* __restrict__ out0,
                             float* __restrict__ out1, int Nrows) {
    int idx = blockIdx.x*blockDim.x + threadIdx.x;
    if (idx >= Nrows*20) return;
    int o = idx % 20, n = idx / 20;
    const float* mp = m + (size_t)n*1024;
    const float* wp = cw + (size_t)o*1024;
    float s = cb[o];
    for (int c=0;c<1024;++c) s += mp[c]*wp[c];
    float v = 1.f/(1.f+expf(-s));
    out0[idx] = v;
    if (out1) out1[idx] = v;
}

// ---------------- cam ----------------
__global__ void cam_kernel(const float* __restrict__ act, const float* __restrict__ cw,
                           const float* __restrict__ cb, float* __restrict__ cam, int N) {
    int idx = blockIdx.x*blockDim.x + threadIdx.x;
    if (idx >= N*20*64) return;
    int p = idx & 63; int o = (idx>>6) % 20; int n = idx / 1280;
    const float* a = act + (size_t)n*1024*64 + p;
    const float* wp = cw + (size_t)o*1024;
    float s = cb[o];
    for (int c=0;c<1024;++c) s += a[c*64]*wp[c];
    cam[idx] = 1.f/(1.f+expf(-s));
}

// ---------------- bilinear resize cam ----------------
__global__ void resize_cam(const float* __restrict__ cam, float* __restrict__ cs, int N) {
    int idx = blockIdx.x*blockDim.x + threadIdx.x;
    if (idx >= N*20*16384) return;
    int xo = idx & 127, yo = (idx>>7)&127;
    int bo = idx >> 14;
    float fy = (float)yo * (7.0f/127.0f);
    float fx = (float)xo * (7.0f/127.0f);
    int y0 = (int)floorf(fy); float wy = fy - (float)y0;
    int x0 = (int)floorf(fx); float wx = fx - (float)x0;
    if (y0 > 7) y0 = 7; if (y0 < 0) y0 = 0; int y1 = min(y0+1, 7);
    if (x0 > 7) x0 = 7; if (x0 < 0) x0 = 0; int x1 = min(x0+1, 7);
    const float* c = cam + (size_t)bo*64;
    float v = (1.f-wy)*((1.f-wx)*c[y0*8+x0] + wx*c[y0*8+x1])
            +      wy *((1.f-wx)*c[y1*8+x0] + wx*c[y1*8+x1]);
    cs[idx] = v;
}

// ---------------- wscore / hscore max reductions ----------------
__global__ void score_maxred(const float* __restrict__ cs, float* __restrict__ wsc,
                             float* __restrict__ hsc, int N) {
    int idx = blockIdx.x*blockDim.x + threadIdx.x;
    int total = N*20*128;
    if (idx >= 2*total) return;
    if (idx < total) {
        int wcol = idx % 128; int bo = idx / 128;
        const float* p = cs + (size_t)bo*16384 + wcol;
        float mv = -1e30f;
        for (int h=0; h<128; ++h) mv = fmaxf(mv, p[h*128]);
        wsc[idx] = mv;
    } else {
        int i = idx - total;
        int hrow = i % 128; int bo = i / 128;
        const float* p = cs + (size_t)bo*16384 + hrow*128;
        float mv = -1e30f;
        for (int w_=0; w_<128; ++w_) mv = fmaxf(mv, p[w_]);
        hsc[i] = mv;
    }
}

// ---------------- stable top-4 of 20 per batch ----------------
__global__ void topk4(const float* __restrict__ gs, int* __restrict__ top, int N) {
    int n = threadIdx.x;
    if (n >= N) return;
    const float* g = gs + n*20;
    bool used[20];
    for (int i=0;i<20;++i) used[i]=false;
    for (int t=0;t<4;++t) {
        int bi = -1; float bv = -1e30f;
        for (int i=0;i<20;++i) {
            if (!used[i] && g[i] > bv) { bv = g[i]; bi = i; }
        }
        used[bi] = true;
        top[n*4+t] = bi;
    }
}

// ---------------- gather top rows + norm01 ----------------
__global__ void gather_norm(const float* __restrict__ wsc, const float* __restrict__ hsc,
                            const int* __restrict__ top, float* __restrict__ xs,
                            float* __restrict__ ysn, int N) {
    int r = blockIdx.x;
    int axis = r / (N*4); int row = r % (N*4);
    int b = row / 4;
    int cls = top[row];
    const float* src = (axis==0 ? wsc : hsc) + ((size_t)b*20 + cls)*128;
    int t = threadIdx.x;
    float v = src[t];
    __shared__ float smn[128], smx[128];
    smn[t] = v; smx[t] = v;
    __syncthreads();
    for (int off=64; off>0; off>>=1) {
        if (t < off) { smn[t] = fminf(smn[t], smn[t+off]); smx[t] = fmaxf(smx[t], smx[t+off]); }
        __syncthreads();
    }
    float mn = smn[0], mx = smx[0];
    float outv;
    if (mx == mn) outv = v / (mx == 0.f ? 1.f : mx);
    else          outv = (v - mn) / (mx - mn);
    (axis==0 ? xs : ysn)[row*128 + t] = outv;
}

// ---------------- obj_loc ----------------
__global__ void objloc(const float* __restrict__ xs, const float* __restrict__ ysn,
                       int* __restrict__ box, int N) {
    int i = threadIdx.x;
    if (i >= 2*N*4) return;
    int axis = i / (N*4); int row = i % (N*4);
    const float* s = (axis ? ysn : xs) + (size_t)row*128;
    const int S = 128, minsize = 16;
    int pos[127]; int ncross = 0;
    int prev = sgnf(s[0] - 0.5f);
    for (int k=1; k<S; ++k) {
        int cur = sgnf(s[k] - 0.5f);
        int d = cur - prev; if (d < 0) d = -d;
        if (d == 2) pos[ncross++] = k-1;
        prev = cur;
    }
    float m = -1e30f;
    for (int k=0; k<S; ++k) m = fmaxf(m, s[k]);
    int zmin = 0, zmax = S, bestkey = -2;
    int a = 0;
    for (int j=0; j<=ncross; ++j) {
        int bnd = (j < ncross) ? pos[j] : S;
        float sm = -1e30f;
        for (int k=a; k<bnd; ++k) sm = fmaxf(sm, s[k]);
        int len = bnd - a;
        int key = (sm == m) ? len : -1;
        if (key > bestkey) { bestkey = key; zmin = a; zmax = bnd; }
        a = bnd;
    }
    bool need = (zmax - zmin) <= minsize;
    int pad = minsize - (zmax - zmin);
    int cp = (pad + 1) >> 1;
    bool c1 = need && (zmin > cp) && (S - zmax > pad);
    if (c1) { zmin = zmin - cp + 1; zmax = zmax + cp; }
    bool c2 = need && (zmin < cp);
    if (c2) { zmin = 0; zmax = minsize; }
    bool c3 = need && (S - zmax < cp);
    if (c3) { zmin = S - minsize + 1; zmax = S; }
    if (ncross == 0) { zmin = minsize; zmax = 112; }
    if (axis == 0) { box[row] = zmin; box[32+row] = zmax; }
    else           { box[64+row] = zmin; box[96+row] = zmax; }
}

// ---------------- crop + bilinear resize ----------------
__global__ void crop_resize_k(const float* __restrict__ x, const int* __restrict__ box,
                              float* __restrict__ lin, int N) {
    int idx = blockIdx.x*blockDim.x + threadIdx.x;
    if (idx >= N*4*3*16384) return;
    int xo = idx & 127, yo = (idx>>7)&127;
    int c  = (idx>>14) % 3;
    int r  = idx / 49152;
    int b  = r / 4;
    int cx1 = box[r],    cx2 = box[32+r];
    int cy1 = box[64+r], cy2 = box[96+r];
    float fy = (float)cy1 + (float)(yo * (cy2 - 1 - cy1)) / 127.0f;
    float fx = (float)cx1 + (float)(xo * (cx2 - 1 - cx1)) / 127.0f;
    float wy = fy - floorf(fy);
    float wx = fx - floorf(fx);
    int y0 = min(max((int)floorf(fy), 0), 127); int y1 = min(y0 + 1, 127);
    int x0 = min(max((int)floorf(fx), 0), 127); int x1 = min(x0 + 1, 127);
    const float* img = x + ((size_t)b*3 + c)*16384;
    float v = (1.f-wy)*((1.f-wx)*img[y0*128+x0] + wx*img[y0*128+x1])
            +      wy *((1.f-wx)*img[y1*128+x0] + wx*img[y1*128+x1]);
    lin[idx] = v;
}

// ---------------- local_stream = max over TOPN ----------------
__global__ void local_stream_max(const float* __restrict__ loc, float* __restrict__ out, int N) {
    int idx = threadIdx.x;
    if (idx >= N*20) return;
    int o = idx % 20, b = idx / 20;
    float mv = -1e30f;
    for (int t=0; t<4; ++t) mv = fmaxf(mv, loc[((size_t)(b*4+t))*20 + o]);
    out[idx] = mv;
}

// ---------------- f32 conv stack (global branch / fallback) ----------------
static void run_stack_f32(const float* input, int n,
                          const float* c1w, const float* bng, const float* bnb,
                          const float* bnm, const float* bnv,
                          const float* w1, const float* w2, const float* w3, const float* w4,
                          float* bufA, float* bufB, float* act, hipStream_t stream) {
    conv7_bn_tiled<float><<<4*4*8*n, 256, 0, stream>>>(input, c1w, bng, bnb, bnm, bnv, bufA, n);
    conv3_tiled<1,16,16,16,8,512,24><<<4*4*8*n, 512, 0, stream>>>(bufA, w1, bufB, n, 64, 128, 64,64, 64,64);
    conv3_tiled<2,8,8,32,8,256,20><<<4*4*8*n, 256, 0, stream>>>(bufB, w2, bufA, n, 128, 256, 64,64, 32,32);
    conv3_tiled<2,8,8,16,8,128,20><<<2*2*32*n, 128, 0, stream>>>(bufA, w3, bufB, n, 256, 512, 32,32, 16,16);
    conv3_tiled<2,8,8,16,8,128,20><<<1*1*64*n, 128, 0, stream>>>(bufB, w4, act, n, 512, 1024, 16,16, 8,8);
}

// ---------------- launcher ----------------
extern "C" void kernel_launch(void* const* d_in, const int* in_sizes, int n_in,
                              void* d_out_, int out_size, void* d_ws, size_t ws_size,
                              hipStream_t stream) {
    const float* x    = (const float*)d_in[0];
    const float* c1w  = (const float*)d_in[1];
    const float* bng  = (const float*)d_in[2];
    const float* bnb  = (const float*)d_in[3];
    const float* bnm  = (const float*)d_in[4];
    const float* bnv  = (const float*)d_in[5];
    const float* w1   = (const float*)d_in[6];
    const float* w2   = (const float*)d_in[7];
    const float* w3   = (const float*)d_in[8];
    const float* w4   = (const float*)d_in[9];
    const float* clsw = (const float*)d_in[10];
    const float* clsb = (const float*)d_in[11];
    float* dout = (float*)d_out_;

    float* out_gs = dout + 0;
    float* out_ls = dout + 160;
    float* out_cs = dout + 320;
    float* out_ws = dout + 2621760;
    float* out_hs = dout + 2642240;
    float* out_li = dout + 2662720;

    const size_t NEED = 101662720ull;   // fast-path ws bytes
    if (ws_size >= NEED) {
        char* wsb = (char*)d_ws;
        ushort* wb1 = (ushort*)(wsb + 0);
        ushort* wb2 = (ushort*)(wsb + 147456);
        ushort* wb3 = (ushort*)(wsb + 737280);
        ushort* wb4 = (ushort*)(wsb + 3096576);
        ushort* R1  = (ushort*)(wsb + 12533760);   // conv7o_l / w2o_l / w4o_l (bf16 NCHW)
        ushort* R2  = (ushort*)(wsb + 29310976);   // w1o_l / w3o_l
        ushort* BR  = (ushort*)(wsb + 62865408);   // im2row region (37.75MB)
        // global-branch f32 scratch overlaps BR (dead before local GEMMs start)
        float* gA   = (float*)(wsb + 62865408);
        float* gB   = (float*)(wsb + 62865408 + 8388608);
        float* gact = (float*)(wsb + 62865408 + 25165824);
        char* smb = wsb + 100614144;
        float* gmean = (float*)(smb);
        float* gst   = (float*)(smb + 32768);
        float* cam   = (float*)(smb + 33408);
        int*   top   = (int*)  (smb + 74368);
        float* xs    = (float*)(smb + 74496);
        float* ysn   = (float*)(smb + 90880);
        int*   box   = (int*)  (smb + 107264);
        float* lmean = (float*)(smb + 107776);
        float* locf  = (float*)(smb + 238848);

        // weights -> bf16 (natural flatten [Co][Ci*9] is the GEMM A matrix)
        wcast<<<288,256,0,stream>>>(w1, wb1, 73728);
        wcast<<<1152,256,0,stream>>>(w2, wb2, 294912);
        wcast<<<4608,256,0,stream>>>(w3, wb3, 1179648);
        wcast<<<18432,256,0,stream>>>(w4, wb4, 4718592);

        // ---- global branch (f32, feeds discrete decisions) ----
        run_stack_f32(x, 8, c1w, bng, bnb, bnm, bnv, w1, w2, w3, w4, gA, gB, gact, stream);
        row_mean64<float><<<2048,256,0,stream>>>(gact, gmean, 8192);
        head_sigmoid<<<1,256,0,stream>>>(gmean, clsw, clsb, gst, out_gs, 8);
        cam_kernel<<<40,256,0,stream>>>(gact, clsw, clsb, cam, 8);
        resize_cam<<<10240,256,0,stream>>>(cam, out_cs, 8);
        score_maxred<<<160,256,0,stream>>>(out_cs, out_ws, out_hs, 8);
        topk4<<<1,64,0,stream>>>(gst, top, 8);
        gather_norm<<<64,128,0,stream>>>(out_ws, out_hs, top, xs, ysn, 8);
        objloc<<<1,64,0,stream>>>(xs, ysn, box, 8);
        crop_resize_k<<<6144,256,0,stream>>>(x, box, out_li, 8);

        // ---- local branch (bf16 MFMA; only feeds mean->head->sigmoid->max) ----
        conv7_bn_tiled<ushort><<<4*4*8*32, 256, 0, stream>>>(out_li, c1w, bng, bnb, bnm, bnv, R1, 32);
        // w1: 64->128 @64x64 s1, 4 chunks of 8 images
        for (int c = 0; c < 4; ++c) {
            im2row_k<<<9216,256,0,stream>>>(R1, BR, c*8, 32768, 64, 64, 64, 64, 64, 1, 576);
            gemm_conv<<<512,256,0,stream>>>(wb1, BR, R2, 128, 576, 32768, 128, 12, c*8);
        }
        // w2: 128->256, 64->32 s2, 2 chunks of 16
        for (int c = 0; c < 2; ++c) {
            im2row_k<<<9216,256,0,stream>>>(R2, BR, c*16, 16384, 128, 64, 64, 32, 32, 2, 1152);
            gemm_conv<<<512,256,0,stream>>>(wb2, BR, R1, 256, 1152, 16384, 256, 10, c*16);
        }
        // w3: 256->512, 32->16 s2, all 32
        im2row_k<<<9216,256,0,stream>>>(R1, BR, 0, 8192, 256, 32, 32, 16, 16, 2, 2304);
        gemm_conv<<<512,256,0,stream>>>(wb3, BR, R2, 512, 2304, 8192, 512, 8, 0);
        // w4: 512->1024, 16->8 s2, all 32
        im2row_k<<<4608,256,0,stream>>>(R2, BR, 0, 2048, 512, 16, 16, 8, 8, 2, 4608);
        gemm_conv<<<256,256,0,stream>>>(wb4, BR, R1, 1024, 4608, 2048, 1024, 6, 0);

        row_mean64<ushort><<<8192,256,0,stream>>>(R1, lmean, 32768);
        head_sigmoid<<<3,256,0,stream>>>(lmean, clsw, clsb, locf, (float*)nullptr, 32);
        local_stream_max<<<1,256,0,stream>>>(locf, out_ls, 8);
    } else {
        // -------- f32 fallback (round-5 verified structure) --------
        float* ws = (float*)d_ws;
        float* bufA  = ws + 0;
        float* bufB  = ws + 2097152;
        float* act   = ws + 6291456;
        float* gmean = ws + 6815744;
        float* gst   = ws + 6823936;
        float* cam   = ws + 6824096;
        int*   top   = (int*)(ws + 6834336);
        float* xs    = ws + 6834368;
        float* ysn   = ws + 6838464;
        int*   box   = (int*)(ws + 6842560);
        float* lmean = ws + 6842688;
        float* locf  = ws + 6875456;

        run_stack_f32(x, 8, c1w, bng, bnb, bnm, bnv, w1, w2, w3, w4, bufA, bufB, act, stream);
        row_mean64<float><<<2048,256,0,stream>>>(act, gmean, 8192);
        head_sigmoid<<<1,256,0,stream>>>(gmean, clsw, clsb, gst, out_gs, 8);
        cam_kernel<<<40,256,0,stream>>>(act, clsw, clsb, cam, 8);
        resize_cam<<<10240,256,0,stream>>>(cam, out_cs, 8);
        score_maxred<<<160,256,0,stream>>>(out_cs, out_ws, out_hs, 8);
        topk4<<<1,64,0,stream>>>(gst, top, 8);
        gather_norm<<<64,128,0,stream>>>(out_ws, out_hs, top, xs, ysn, 8);
        objloc<<<1,64,0,stream>>>(xs, ysn, box, 8);
        crop_resize_k<<<6144,256,0,stream>>>(x, box, out_li, 8);

        for (int c = 0; c < 4; ++c) {
            const float* lin_c = out_li + (size_t)c*8*3*16384;
            run_stack_f32(lin_c, 8, c1w, bng, bnb, bnm, bnv, w1, w2, w3, w4, bufA, bufB, act, stream);
            row_mean64<float><<<2048,256,0,stream>>>(act, lmean + c*8192, 8192);
        }
        head_sigmoid<<<3,256,0,stream>>>(lmean, clsw, clsb, locf, (float*)nullptr, 32);
        local_stream_max<<<1,256,0,stream>>>(locf, out_ls, 8);
    }
}

// Round 7
// 1555.667 us; speedup vs baseline: 18.3865x; 1.3967x over previous
//
#include <hip/hip_runtime.h>
#include <hip/hip_bf16.h>

// ---------------- helpers ----------------
__device__ __forceinline__ int sgnf(float v){ return (v>0.f)-(v<0.f); }
__device__ __forceinline__ ushort f2b(float f){ __hip_bfloat16 h = __float2bfloat16(f); return __builtin_bit_cast(ushort, h); }
__device__ __forceinline__ float  b2f(ushort u){ __hip_bfloat16 h = __builtin_bit_cast(__hip_bfloat16, u); return __bfloat162float(h); }
__device__ __forceinline__ float  tof(float v){ return v; }
__device__ __forceinline__ float  tof(ushort v){ return b2f(v); }

typedef short  s8v  __attribute__((ext_vector_type(8)));
typedef ushort us8  __attribute__((ext_vector_type(8)));
typedef float  f4v  __attribute__((ext_vector_type(4)));

// =====================================================================
// f32 tiled 3x3 conv + relu. RELU=true: full conv, relu'd output.
// RELU=false: partial sum over ci range [blockIdx.y*ciLen, +ciLen),
//             raw f32 written to slab blockIdx.y (no relu).
// =====================================================================
template<int STRIDE, int TH, int TW, int CO_T, int CI_T, int NT, int P, bool RELU>
__global__ __launch_bounds__(NT) void conv3_tiled(
    const float* __restrict__ in, const float* __restrict__ w, float* __restrict__ out,
    int N, int Ci, int Co, int Hi, int Wi, int Ho, int Wo, int ciLen)
{
    constexpr int NSP   = (TH/2)*(TW/4);
    constexpr int IT_H  = (TH-1)*STRIDE + 3;
    constexpr int IT_W  = (TW-1)*STRIDE + 3;
    constexpr int IN_ELEMS = CI_T*IT_H*IT_W;
    constexpr int W_ELEMS  = CI_T*CO_T*9;
    static_assert(NSP*CO_T == NT, "thread count mismatch");
    static_assert(IT_W <= P, "pitch too small");

    __shared__ __align__(16) float s_in[CI_T*IT_H*P];
    __shared__ __align__(16) float s_w[CI_T*CO_T*12];

    int bx = blockIdx.x;
    const int spxn = Wo/TW, spyn = Ho/TH, cog = Co/CO_T;
    const int sxb = bx % spxn; bx /= spxn;
    const int syb = bx % spyn; bx /= spyn;
    const int cg  = bx % cog;  const int n = bx / cog;
    const int tx0 = sxb*TW, ty0 = syb*TH, co0 = cg*CO_T;

    const int ciStart = RELU ? 0 : blockIdx.y * ciLen;
    const int ciEnd   = RELU ? Ci : ciStart + ciLen;
    if (!RELU) out += (size_t)blockIdx.y * N * Co * Ho * Wo;

    const int tid = threadIdx.x;
    const int sp  = tid % NSP;
    const int co  = tid / NSP;
    const int sy  = (sp / (TW/4)) * 2;
    const int sx  = (sp % (TW/4)) * 4;

    const int y_in0 = ty0*STRIDE - 1, x_in0 = tx0*STRIDE - 1;
    const float* in_n = in + (size_t)n*Ci*Hi*Wi;

    float acc[2][4] = {{0.f,0.f,0.f,0.f},{0.f,0.f,0.f,0.f}};

    for (int ci0 = ciStart; ci0 < ciEnd; ci0 += CI_T) {
        for (int idx = tid; idx < IN_ELEMS; idx += NT) {
            int ci  = idx / (IT_H*IT_W);
            int rem = idx - ci*(IT_H*IT_W);
            int iy  = rem / IT_W;
            int ix  = rem - iy*IT_W;
            int gy = y_in0 + iy, gx = x_in0 + ix;
            float v = 0.f;
            if ((unsigned)gy < (unsigned)Hi && (unsigned)gx < (unsigned)Wi)
                v = in_n[(size_t)(ci0+ci)*Hi*Wi + gy*Wi + gx];
            s_in[ci*(IT_H*P) + iy*P + ix] = v;
        }
        for (int idx = tid; idx < W_ELEMS; idx += NT) {
            int ci  = idx / (CO_T*9);
            int rem = idx - ci*(CO_T*9);
            int c   = rem / 9, k = rem - c*9;
            s_w[(ci*CO_T + c)*12 + k] = w[((size_t)(co0+c)*Ci + (ci0+ci))*9 + k];
        }
        __syncthreads();

        #pragma unroll
        for (int ci = 0; ci < CI_T; ++ci) {
            const float* wp = &s_w[(ci*CO_T + co)*12];
            float4 wa = *(const float4*)wp;
            float4 wb = *(const float4*)(wp+4);
            float w8  = wp[8];
            float wr[9] = {wa.x,wa.y,wa.z,wa.w, wb.x,wb.y,wb.z,wb.w, w8};
            const float* ip = &s_in[ci*(IT_H*P)];

            if constexpr (STRIDE == 1) {
                #pragma unroll
                for (int pr = 0; pr < 4; ++pr) {
                    const float* row = ip + (sy+pr)*P + sx;
                    float4 a = *(const float4*)row;
                    float2 b = *(const float2*)(row+4);
                    float e[6] = {a.x,a.y,a.z,a.w,b.x,b.y};
                    #pragma unroll
                    for (int ky = 0; ky < 3; ++ky) {
                        int ry = pr - ky;
                        if (ry == 0 || ry == 1) {
                            #pragma unroll
                            for (int kx = 0; kx < 3; ++kx)
                                #pragma unroll
                                for (int rx = 0; rx < 4; ++rx)
                                    acc[ry][rx] += e[rx+kx] * wr[ky*3+kx];
                        }
                    }
                }
            } else {
                #pragma unroll
                for (int pr = 0; pr < 5; ++pr) {
                    const float* row = ip + (2*sy+pr)*P + 2*sx;
                    float4 a = *(const float4*)row;
                    float4 b = *(const float4*)(row+4);
                    float c8 = row[8];
                    float e[9] = {a.x,a.y,a.z,a.w,b.x,b.y,b.z,b.w,c8};
                    #pragma unroll
                    for (int ky = 0; ky < 3; ++ky) {
                        int ry2 = pr - ky;
                        if (ry2 == 0 || ry2 == 2) {
                            int ry = ry2 >> 1;
                            #pragma unroll
                            for (int kx = 0; kx < 3; ++kx)
                                #pragma unroll
                                for (int rx = 0; rx < 4; ++rx)
                                    acc[ry][rx] += e[2*rx+kx] * wr[ky*3+kx];
                        }
                    }
                }
            }
        }
        __syncthreads();
    }

    float* op = out + ((size_t)n*Co + co0 + co)*Ho*Wo + (size_t)(ty0+sy)*Wo + (tx0+sx);
    #pragma unroll
    for (int ry=0; ry<2; ++ry) {
        float4 v;
        if constexpr (RELU) {
            v.x = fmaxf(acc[ry][0], 0.f); v.y = fmaxf(acc[ry][1], 0.f);
            v.z = fmaxf(acc[ry][2], 0.f); v.w = fmaxf(acc[ry][3], 0.f);
        } else {
            v.x = acc[ry][0]; v.y = acc[ry][1]; v.z = acc[ry][2]; v.w = acc[ry][3];
        }
        *(float4*)(op + (size_t)ry*Wo) = v;
    }
}

// ---------------- sum K partial slabs + relu ----------------
__global__ void reduce_relu(const float* __restrict__ part, float* __restrict__ out,
                            int L, int KS) {
    int i = (blockIdx.x*blockDim.x + threadIdx.x) * 4;
    if (i >= L) return;
    float4 s = *(const float4*)&part[i];
    for (int k = 1; k < KS; ++k) {
        float4 p = *(const float4*)&part[(size_t)k*L + i];
        s.x += p.x; s.y += p.y; s.z += p.z; s.w += p.w;
    }
    s.x = fmaxf(s.x, 0.f); s.y = fmaxf(s.y, 0.f);
    s.z = fmaxf(s.z, 0.f); s.w = fmaxf(s.w, 0.f);
    *(float4*)&out[i] = s;
}

// =====================================================================
// 7x7 s2 p3 conv + BN (f32 math). TO = float (global) or ushort bf16 (local)
// =====================================================================
template<typename TO>
__global__ __launch_bounds__(256) void conv7_bn_tiled(
    const float* __restrict__ x, const float* __restrict__ w,
    const float* __restrict__ gamma, const float* __restrict__ beta,
    const float* __restrict__ mean, const float* __restrict__ var,
    TO* __restrict__ out, int N)
{
    constexpr int TH=16, TW=16, CO_T=8, NT=256, NSP=32;
    constexpr int IT = 37;
    constexpr int P  = 38;
    constexpr int IN_ELEMS = 3*IT*IT;
    constexpr int W_ELEMS  = CO_T*3*49;

    __shared__ __align__(16) float s_in[3*IT*P];
    __shared__ __align__(16) float s_w[CO_T*3*7*8];

    int bx = blockIdx.x;
    const int spn = 4, cog = 8;
    const int sxb = bx % spn; bx /= spn;
    const int syb = bx % spn; bx /= spn;
    const int cg  = bx % cog; const int n = bx / cog;
    const int tx0 = sxb*TW, ty0 = syb*TH, co0 = cg*CO_T;

    const int tid = threadIdx.x;
    const int sp  = tid % NSP;
    const int co  = tid / NSP;
    const int sy  = (sp / 4) * 2;
    const int sx  = (sp % 4) * 4;

    const int y_in0 = ty0*2 - 3, x_in0 = tx0*2 - 3;
    const float* x_n = x + (size_t)n*3*16384;

    for (int idx = tid; idx < IN_ELEMS; idx += NT) {
        int ci  = idx / (IT*IT);
        int rem = idx - ci*(IT*IT);
        int iy  = rem / IT;
        int ix  = rem - iy*IT;
        int gy = y_in0 + iy, gx = x_in0 + ix;
        float v = 0.f;
        if ((unsigned)gy < 128u && (unsigned)gx < 128u)
            v = x_n[(size_t)ci*16384 + gy*128 + gx];
        s_in[ci*(IT*P) + iy*P + ix] = v;
    }
    for (int idx = tid; idx < W_ELEMS; idx += NT) {
        int c   = idx / 147;
        int rem = idx - c*147;
        int ci  = rem / 49;
        int rem2= rem - ci*49;
        int ky  = rem2 / 7, kx = rem2 - ky*7;
        s_w[((c*3 + ci)*7 + ky)*8 + kx] = w[(size_t)(co0+c)*147 + ci*49 + ky*7 + kx];
    }
    __syncthreads();

    float acc[2][4] = {{0.f,0.f,0.f,0.f},{0.f,0.f,0.f,0.f}};
    const int c0 = 2*sx;
    #pragma unroll 1
    for (int ci = 0; ci < 3; ++ci) {
        const float* ip = &s_in[ci*(IT*P)];
        #pragma unroll
        for (int pr = 0; pr < 9; ++pr) {
            const float* row = ip + (2*sy+pr)*P + c0;
            float2 q0 = *(const float2*)(row+0);
            float2 q1 = *(const float2*)(row+2);
            float2 q2 = *(const float2*)(row+4);
            float2 q3 = *(const float2*)(row+6);
            float2 q4 = *(const float2*)(row+8);
            float2 q5 = *(const float2*)(row+10);
            float  e12 = row[12];
            float e[13] = {q0.x,q0.y,q1.x,q1.y,q2.x,q2.y,q3.x,q3.y,q4.x,q4.y,q5.x,q5.y,e12};
            #pragma unroll
            for (int ry = 0; ry < 2; ++ry) {
                int ky = pr - 2*ry;
                if (ky >= 0 && ky < 7) {
                    const float* wrow = &s_w[((co*3 + ci)*7 + ky)*8];
                    float4 wa = *(const float4*)wrow;
                    float2 wbv = *(const float2*)(wrow+4);
                    float w6 = wrow[6];
                    float wk[7] = {wa.x,wa.y,wa.z,wa.w,wbv.x,wbv.y,w6};
                    #pragma unroll
                    for (int kx = 0; kx < 7; ++kx)
                        #pragma unroll
                        for (int rx = 0; rx < 4; ++rx)
                            acc[ry][rx] += e[2*rx+kx] * wk[kx];
                }
            }
        }
    }

    const int coo = co0 + co;
    float inv = gamma[coo] / sqrtf(var[coo] + 1e-5f);
    float mu = mean[coo], bb = beta[coo];
    TO* op = out + ((size_t)n*64 + coo)*4096 + (size_t)(ty0+sy)*64 + (tx0+sx);
    #pragma unroll
    for (int ry=0; ry<2; ++ry) {
        float v0 = (acc[ry][0]-mu)*inv + bb; float v1 = (acc[ry][1]-mu)*inv + bb;
        float v2 = (acc[ry][2]-mu)*inv + bb; float v3 = (acc[ry][3]-mu)*inv + bb;
        if constexpr (sizeof(TO) == 4) {
            float4 v; v.x=v0; v.y=v1; v.z=v2; v.w=v3;
            *(float4*)((float*)op + (size_t)ry*64) = v;
        } else {
            ushort4 u; u.x=f2b(v0); u.y=f2b(v1); u.z=f2b(v2); u.w=f2b(v3);
            *(ushort4*)((ushort*)op + (size_t)ry*64) = u;
        }
    }
}

// ---------------- weight f32 -> bf16 cast ----------------
__global__ void wcast(const float* __restrict__ src, ushort* __restrict__ dst, int n) {
    int i = blockIdx.x*blockDim.x + threadIdx.x;
    if (i < n) dst[i] = f2b(src[i]);
}

// ---------------- im2row (bf16 NCHW -> Brow[p][k]) ----------------
__global__ void im2row_k(const ushort* __restrict__ in, ushort* __restrict__ Brow,
                         int n0, int NN, int Ci, int Hi, int Wi, int Ho, int Wo,
                         int stride, int K) {
    int idx = blockIdx.x*blockDim.x + threadIdx.x;
    int K8 = K >> 3;
    if (idx >= NN * K8) return;
    int ks = idx % K8;
    int p  = idx / K8;
    int xo = p % Wo; int t = p / Wo; int yo = t % Ho; int nl = t / Ho;
    const ushort* ip = in + (size_t)(n0 + nl)*Ci*Hi*Wi;
    int y0 = yo*stride - 1, x0 = xo*stride - 1;
    us8 v;
    #pragma unroll
    for (int j = 0; j < 8; ++j) {
        int k = ks*8 + j;
        int ci = k / 9, tt = k - ci*9;
        int ky = tt / 3, kx = tt - ky*3;
        int yi = y0 + ky, xi = x0 + kx;
        ushort val = 0;
        if ((unsigned)yi < (unsigned)Hi && (unsigned)xi < (unsigned)Wi)
            val = ip[(size_t)ci*Hi*Wi + yi*Wi + xi];
        v[j] = val;
    }
    *(us8*)&Brow[(size_t)p*K + ks*8] = v;
}

// ---------------- bf16 MFMA GEMM (verified round 6) ----------------
__global__ __launch_bounds__(256) void gemm_conv(
    const ushort* __restrict__ A, const ushort* __restrict__ B,
    ushort* __restrict__ out,
    int M, int K, int NN, int Co, int hwShift, int n0)
{
    __shared__ __align__(16) ushort sA[64*32];
    __shared__ __align__(16) ushort sB[128*32];

    int bx = blockIdx.x;
    int mtiles = M >> 6;
    int mt = bx % mtiles;
    int nt = bx / mtiles;
    int co0 = mt << 6, p0 = nt << 7;
    int tid = threadIdx.x, lane = tid & 63, wave = tid >> 6;
    int wm = wave & 1, wn = wave >> 1;

    f4v acc[2][4];
    #pragma unroll
    for (int i=0;i<2;++i)
        #pragma unroll
        for (int j=0;j<4;++j)
            #pragma unroll
            for (int r=0;r<4;++r) acc[i][j][r] = 0.f;

    const int g  = lane >> 4;
    const int li = lane & 15;

    for (int k0 = 0; k0 < K; k0 += 32) {
        {
            int r = tid >> 2, s = tid & 3;
            int sp = s ^ ((r >> 1) & 3);
            us8 val = *(const us8*)&A[(size_t)(co0 + r)*K + k0 + s*8];
            *(us8*)&sA[r*32 + sp*8] = val;
        }
        #pragma unroll
        for (int h = 0; h < 2; ++h) {
            int slot = tid + h*256;
            int r = slot >> 2, s = slot & 3;
            int sp = s ^ ((r >> 1) & 3);
            us8 val = *(const us8*)&B[(size_t)(p0 + r)*K + k0 + s*8];
            *(us8*)&sB[r*32 + sp*8] = val;
        }
        __syncthreads();

        s8v a0, a1, b0, b1, b2, b3;
        {
            int r = wm*32 + li;
            a0 = *(const s8v*)&sA[r*32 + ((g ^ ((r>>1)&3)))*8];
            int r2 = r + 16;
            a1 = *(const s8v*)&sA[r2*32 + ((g ^ ((r2>>1)&3)))*8];
        }
        {
            int r = wn*64 + li;
            b0 = *(const s8v*)&sB[r*32 + ((g ^ ((r>>1)&3)))*8];
            int r1 = r + 16;
            b1 = *(const s8v*)&sB[r1*32 + ((g ^ ((r1>>1)&3)))*8];
            int r2 = r + 32;
            b2 = *(const s8v*)&sB[r2*32 + ((g ^ ((r2>>1)&3)))*8];
            int r3 = r + 48;
            b3 = *(const s8v*)&sB[r3*32 + ((g ^ ((r3>>1)&3)))*8];
        }
        acc[0][0] = __builtin_amdgcn_mfma_f32_16x16x32_bf16(a0, b0, acc[0][0], 0, 0, 0);
        acc[0][1] = __builtin_amdgcn_mfma_f32_16x16x32_bf16(a0, b1, acc[0][1], 0, 0, 0);
        acc[0][2] = __builtin_amdgcn_mfma_f32_16x16x32_bf16(a0, b2, acc[0][2], 0, 0, 0);
        acc[0][3] = __builtin_amdgcn_mfma_f32_16x16x32_bf16(a0, b3, acc[0][3], 0, 0, 0);
        acc[1][0] = __builtin_amdgcn_mfma_f32_16x16x32_bf16(a1, b0, acc[1][0], 0, 0, 0);
        acc[1][1] = __builtin_amdgcn_mfma_f32_16x16x32_bf16(a1, b1, acc[1][1], 0, 0, 0);
        acc[1][2] = __builtin_amdgcn_mfma_f32_16x16x32_bf16(a1, b2, acc[1][2], 0, 0, 0);
        acc[1][3] = __builtin_amdgcn_mfma_f32_16x16x32_bf16(a1, b3, acc[1][3], 0, 0, 0);
        __syncthreads();
    }

    int hwMask = (1 << hwShift) - 1;
    #pragma unroll
    for (int i = 0; i < 2; ++i) {
        #pragma unroll
        for (int j = 0; j < 4; ++j) {
            #pragma unroll
            for (int r = 0; r < 4; ++r) {
                int co = co0 + wm*32 + i*16 + g*4 + r;
                int p  = p0 + wn*64 + j*16 + li;
                int nimg = p >> hwShift, sphw = p & hwMask;
                float v = fmaxf(acc[i][j][r], 0.f);
                out[(((size_t)(n0 + nimg)*Co + co) << hwShift) + sphw] = f2b(v);
            }
        }
    }
}

// ---------------- per-row (64-elem) mean via wave reduce ----------------
template<typename T>
__global__ void row_mean64(const T* __restrict__ in, float* __restrict__ out, int rows) {
    int w = (blockIdx.x*blockDim.x + threadIdx.x) >> 6;
    int lane = threadIdx.x & 63;
    if (w >= rows) return;
    float v = tof(in[(size_t)w*64 + lane]);
    #pragma unroll
    for (int off = 32; off > 0; off >>= 1) v += __shfl_down(v, off, 64);
    if (lane == 0) out[w] = v * (1.f/64.f);
}

// ---------------- classifier head ----------------
__global__ void head_sigmoid(const float* __restrict__ m, const float* __restrict__ cw,
                             const float* __restrict__ cb, float* __restrict__ out0,
                             float* __restrict__ out1, int Nrows) {
    int idx = blockIdx.x*blockDim.x + threadIdx.x;
    if (idx >= Nrows*20) return;
    int o = idx % 20, n = idx / 20;
    const float* mp = m + (size_t)n*1024;
    const float* wp = cw + (size_t)o*1024;
    float s = cb[o];
    for (int c=0;c<1024;++c) s += mp[c]*wp[c];
    float v = 1.f/(1.f+expf(-s));
    out0[idx] = v;
    if (out1) out1[idx] = v;
}

// ---------------- cam ----------------
__global__ void cam_kernel(const float* __restrict__ act, const float* __restrict__ cw,
                           const float* __restrict__ cb, float* __restrict__ cam, int N) {
    int idx = blockIdx.x*blockDim.x + threadIdx.x;
    if (idx >= N*20*64) return;
    int p = idx & 63; int o = (idx>>6) % 20; int n = idx / 1280;
    const float* a = act + (size_t)n*1024*64 + p;
    const float* wp = cw + (size_t)o*1024;
    float s = cb[o];
    for (int c=0;c<1024;++c) s += a[c*64]*wp[c];
    cam[idx] = 1.f/(1.f+expf(-s));
}

// ---------------- bilinear resize cam ----------------
__global__ void resize_cam(const float* __restrict__ cam, float* __restrict__ cs, int N) {
    int idx = blockIdx.x*blockDim.x + threadIdx.x;
    if (idx >= N*20*16384) return;
    int xo = idx & 127, yo = (idx>>7)&127;
    int bo = idx >> 14;
    float fy = (float)yo * (7.0f/127.0f);
    float fx = (float)xo * (7.0f/127.0f);
    int y0 = (int)floorf(fy); float wy = fy - (float)y0;
    int x0 = (int)floorf(fx); float wx = fx - (float)x0;
    if (y0 > 7) y0 = 7; if (y0 < 0) y0 = 0; int y1 = min(y0+1, 7);
    if (x0 > 7) x0 = 7; if (x0 < 0) x0 = 0; int x1 = min(x0+1, 7);
    const float* c = cam + (size_t)bo*64;
    float v = (1.f-wy)*((1.f-wx)*c[y0*8+x0] + wx*c[y0*8+x1])
            +      wy *((1.f-wx)*c[y1*8+x0] + wx*c[y1*8+x1]);
    cs[idx] = v;
}

// ---------------- wscore / hscore max reductions ----------------
__global__ void score_maxred(const float* __restrict__ cs, float* __restrict__ wsc,
                             float* __restrict__ hsc, int N) {
    int idx = blockIdx.x*blockDim.x + threadIdx.x;
    int total = N*20*128;
    if (idx >= 2*total) return;
    if (idx < total) {
        int wcol = idx % 128; int bo = idx / 128;
        const float* p = cs + (size_t)bo*16384 + wcol;
        float mv = -1e30f;
        for (int h=0; h<128; ++h) mv = fmaxf(mv, p[h*128]);
        wsc[idx] = mv;
    } else {
        int i = idx - total;
        int hrow = i % 128; int bo = i / 128;
        const float* p = cs + (size_t)bo*16384 + hrow*128;
        float mv = -1e30f;
        for (int w_=0; w_<128; ++w_) mv = fmaxf(mv, p[w_]);
        hsc[i] = mv;
    }
}

// ---------------- stable top-4 of 20 per batch ----------------
__global__ void topk4(const float* __restrict__ gs, int* __restrict__ top, int N) {
    int n = threadIdx.x;
    if (n >= N) return;
    const float* g = gs + n*20;
    bool used[20];
    for (int i=0;i<20;++i) used[i]=false;
    for (int t=0;t<4;++t) {
        int bi = -1; float bv = -1e30f;
        for (int i=0;i<20;++i) {
            if (!used[i] && g[i] > bv) { bv = g[i]; bi = i; }
        }
        used[bi] = true;
        top[n*4+t] = bi;
    }
}

// ---------------- gather top rows + norm01 ----------------
__global__ void gather_norm(const float* __restrict__ wsc, const float* __restrict__ hsc,
                            const int* __restrict__ top, float* __restrict__ xs,
                            float* __restrict__ ysn, int N) {
    int r = blockIdx.x;
    int axis = r / (N*4); int row = r % (N*4);
    int b = row / 4;
    int cls = top[row];
    const float* src = (axis==0 ? wsc : hsc) + ((size_t)b*20 + cls)*128;
    int t = threadIdx.x;
    float v = src[t];
    __shared__ float smn[128], smx[128];
    smn[t] = v; smx[t] = v;
    __syncthreads();
    for (int off=64; off>0; off>>=1) {
        if (t < off) { smn[t] = fminf(smn[t], smn[t+off]); smx[t] = fmaxf(smx[t], smx[t+off]); }
        __syncthreads();
    }
    float mn = smn[0], mx = smx[0];
    float outv;
    if (mx == mn) outv = v / (mx == 0.f ? 1.f : mx);
    else          outv = (v - mn) / (mx - mn);
    (axis==0 ? xs : ysn)[row*128 + t] = outv;
}

// ---------------- obj_loc ----------------
__global__ void objloc(const float* __restrict__ xs, const float* __restrict__ ysn,
                       int* __restrict__ box, int N) {
    int i = threadIdx.x;
    if (i >= 2*N*4) return;
    int axis = i / (N*4); int row = i % (N*4);
    const float* s = (axis ? ysn : xs) + (size_t)row*128;
    const int S = 128, minsize = 16;
    int pos[127]; int ncross = 0;
    int prev = sgnf(s[0] - 0.5f);
    for (int k=1; k<S; ++k) {
        int cur = sgnf(s[k] - 0.5f);
        int d = cur - prev; if (d < 0) d = -d;
        if (d == 2) pos[ncross++] = k-1;
        prev = cur;
    }
    float m = -1e30f;
    for (int k=0; k<S; ++k) m = fmaxf(m, s[k]);
    int zmin = 0, zmax = S, bestkey = -2;
    int a = 0;
    for (int j=0; j<=ncross; ++j) {
        int bnd = (j < ncross) ? pos[j] : S;
        float sm = -1e30f;
        for (int k=a; k<bnd; ++k) sm = fmaxf(sm, s[k]);
        int len = bnd - a;
        int key = (sm == m) ? len : -1;
        if (key > bestkey) { bestkey = key; zmin = a; zmax = bnd; }
        a = bnd;
    }
    bool need = (zmax - zmin) <= minsize;
    int pad = minsize - (zmax - zmin);
    int cp = (pad + 1) >> 1;
    bool c1 = need && (zmin > cp) && (S - zmax > pad);
    if (c1) { zmin = zmin - cp + 1; zmax = zmax + cp; }
    bool c2 = need && (zmin < cp);
    if (c2) { zmin = 0; zmax = minsize; }
    bool c3 = need && (S - zmax < cp);
    if (c3) { zmin = S - minsize + 1; zmax = S; }
    if (ncross == 0) { zmin = minsize; zmax = 112; }
    if (axis == 0) { box[row] = zmin; box[32+row] = zmax; }
    else           { box[64+row] = zmin; box[96+row] = zmax; }
}

// ---------------- crop + bilinear resize ----------------
__global__ void crop_resize_k(const float* __restrict__ x, const int* __restrict__ box,
                              float* __restrict__ lin, int N) {
    int idx = blockIdx.x*blockDim.x + threadIdx.x;
    if (idx >= N*4*3*16384) return;
    int xo = idx & 127, yo = (idx>>7)&127;
    int c  = (idx>>14) % 3;
    int r  = idx / 49152;
    int b  = r / 4;
    int cx1 = box[r],    cx2 = box[32+r];
    int cy1 = box[64+r], cy2 = box[96+r];
    float fy = (float)cy1 + (float)(yo * (cy2 - 1 - cy1)) / 127.0f;
    float fx = (float)cx1 + (float)(xo * (cx2 - 1 - cx1)) / 127.0f;
    float wy = fy - floorf(fy);
    float wx = fx - floorf(fx);
    int y0 = min(max((int)floorf(fy), 0), 127); int y1 = min(y0 + 1, 127);
    int x0 = min(max((int)floorf(fx), 0), 127); int x1 = min(x0 + 1, 127);
    const float* img = x + ((size_t)b*3 + c)*16384;
    float v = (1.f-wy)*((1.f-wx)*img[y0*128+x0] + wx*img[y0*128+x1])
            +      wy *((1.f-wx)*img[y1*128+x0] + wx*img[y1*128+x1]);
    lin[idx] = v;
}

// ---------------- local_stream = max over TOPN ----------------
__global__ void local_stream_max(const float* __restrict__ loc, float* __restrict__ out, int N) {
    int idx = threadIdx.x;
    if (idx >= N*20) return;
    int o = idx % 20, b = idx / 20;
    float mv = -1e30f;
    for (int t=0; t<4; ++t) mv = fmaxf(mv, loc[((size_t)(b*4+t))*20 + o]);
    out[idx] = mv;
}

// ---------------- f32 conv stack with K-split w3/w4 ----------------
// bufA >= 8.4MB, bufB >= 12.6MB, act >= 2MB (bytes: n=8)
static void run_stack_f32(const float* input, int n,
                          const float* c1w, const float* bng, const float* bnb,
                          const float* bnm, const float* bnv,
                          const float* w1, const float* w2, const float* w3, const float* w4,
                          float* bufA, float* bufB, float* act, hipStream_t stream) {
    float* w3out = bufB + (size_t)n*512*256*2;       // after 2 partial slabs
    // conv1 7x7 s2: (n,3,128,128)->(n,64,64,64)
    conv7_bn_tiled<float><<<4*4*8*n, 256, 0, stream>>>(input, c1w, bng, bnb, bnm, bnv, bufA, n);
    // w1 3x3 s1: 64->128 @64x64
    conv3_tiled<1,16,16,16,8,512,24,true><<<4*4*8*n, 512, 0, stream>>>(bufA, w1, bufB, n, 64, 128, 64,64, 64,64, 0);
    // w2 3x3 s2: 128->256, 64->32
    conv3_tiled<2,8,8,32,8,256,20,true><<<4*4*8*n, 256, 0, stream>>>(bufB, w2, bufA, n, 128, 256, 64,64, 32,32, 0);
    // w3 3x3 s2: 256->512, 32->16  — KS=2 partials into bufB, reduce to w3out
    {
        dim3 grid(2*2*16*n, 2);
        conv3_tiled<2,8,8,32,8,256,20,false><<<grid, 256, 0, stream>>>(bufA, w3, bufB, n, 256, 512, 32,32, 16,16, 128);
        int L = n*512*256;
        reduce_relu<<<(L/4+255)/256, 256, 0, stream>>>(bufB, w3out, L, 2);
    }
    // w4 3x3 s2: 512->1024, 16->8  — KS=4 partials into bufA, reduce to act
    {
        dim3 grid(1*1*32*n, 4);
        conv3_tiled<2,8,8,32,8,256,20,false><<<grid, 256, 0, stream>>>(w3out, w4, bufA, n, 512, 1024, 16,16, 8,8, 128);
        int L = n*1024*64;
        reduce_relu<<<(L/4+255)/256, 256, 0, stream>>>(bufA, act, L, 4);
    }
}

// ---------------- launcher ----------------
extern "C" void kernel_launch(void* const* d_in, const int* in_sizes, int n_in,
                              void* d_out_, int out_size, void* d_ws, size_t ws_size,
                              hipStream_t stream) {
    const float* x    = (const float*)d_in[0];
    const float* c1w  = (const float*)d_in[1];
    const float* bng  = (const float*)d_in[2];
    const float* bnb  = (const float*)d_in[3];
    const float* bnm  = (const float*)d_in[4];
    const float* bnv  = (const float*)d_in[5];
    const float* w1   = (const float*)d_in[6];
    const float* w2   = (const float*)d_in[7];
    const float* w3   = (const float*)d_in[8];
    const float* w4   = (const float*)d_in[9];
    const float* clsw = (const float*)d_in[10];
    const float* clsb = (const float*)d_in[11];
    float* dout = (float*)d_out_;

    float* out_gs = dout + 0;
    float* out_ls = dout + 160;
    float* out_cs = dout + 320;
    float* out_ws = dout + 2621760;
    float* out_hs = dout + 2642240;
    float* out_li = dout + 2662720;

    const size_t NEED = 101662720ull;
    if (ws_size >= NEED) {
        char* wsb = (char*)d_ws;
        ushort* wb1 = (ushort*)(wsb + 0);
        ushort* wb2 = (ushort*)(wsb + 147456);
        ushort* wb3 = (ushort*)(wsb + 737280);
        ushort* wb4 = (ushort*)(wsb + 3096576);
        ushort* R1  = (ushort*)(wsb + 12533760);
        ushort* R2  = (ushort*)(wsb + 29310976);
        ushort* BR  = (ushort*)(wsb + 62865408);
        float* gA   = (float*)(wsb + 62865408);                  // 8.4MB
        float* gB   = (float*)(wsb + 62865408 + 8388608);        // 16.8MB
        float* gact = (float*)(wsb + 62865408 + 25165824);       // 2MB
        char* smb = wsb + 100614144;
        float* gmean = (float*)(smb);
        float* gst   = (float*)(smb + 32768);
        float* cam   = (float*)(smb + 33408);
        int*   top   = (int*)  (smb + 74368);
        float* xs    = (float*)(smb + 74496);
        float* ysn   = (float*)(smb + 90880);
        int*   box   = (int*)  (smb + 107264);
        float* lmean = (float*)(smb + 107776);
        float* locf  = (float*)(smb + 238848);

        wcast<<<288,256,0,stream>>>(w1, wb1, 73728);
        wcast<<<1152,256,0,stream>>>(w2, wb2, 294912);
        wcast<<<4608,256,0,stream>>>(w3, wb3, 1179648);
        wcast<<<18432,256,0,stream>>>(w4, wb4, 4718592);

        // ---- global branch (f32, feeds discrete decisions) ----
        run_stack_f32(x, 8, c1w, bng, bnb, bnm, bnv, w1, w2, w3, w4, gA, gB, gact, stream);
        row_mean64<float><<<2048,256,0,stream>>>(gact, gmean, 8192);
        head_sigmoid<<<1,256,0,stream>>>(gmean, clsw, clsb, gst, out_gs, 8);
        cam_kernel<<<40,256,0,stream>>>(gact, clsw, clsb, cam, 8);
        resize_cam<<<10240,256,0,stream>>>(cam, out_cs, 8);
        score_maxred<<<160,256,0,stream>>>(out_cs, out_ws, out_hs, 8);
        topk4<<<1,64,0,stream>>>(gst, top, 8);
        gather_norm<<<64,128,0,stream>>>(out_ws, out_hs, top, xs, ysn, 8);
        objloc<<<1,64,0,stream>>>(xs, ysn, box, 8);
        crop_resize_k<<<6144,256,0,stream>>>(x, box, out_li, 8);

        // ---- local branch (bf16 MFMA) ----
        conv7_bn_tiled<ushort><<<4*4*8*32, 256, 0, stream>>>(out_li, c1w, bng, bnb, bnm, bnv, R1, 32);
        for (int c = 0; c < 4; ++c) {
            im2row_k<<<9216,256,0,stream>>>(R1, BR, c*8, 32768, 64, 64, 64, 64, 64, 1, 576);
            gemm_conv<<<512,256,0,stream>>>(wb1, BR, R2, 128, 576, 32768, 128, 12, c*8);
        }
        for (int c = 0; c < 2; ++c) {
            im2row_k<<<9216,256,0,stream>>>(R2, BR, c*16, 16384, 128, 64, 64, 32, 32, 2, 1152);
            gemm_conv<<<512,256,0,stream>>>(wb2, BR, R1, 256, 1152, 16384, 256, 10, c*16);
        }
        im2row_k<<<9216,256,0,stream>>>(R1, BR, 0, 8192, 256, 32, 32, 16, 16, 2, 2304);
        gemm_conv<<<512,256,0,stream>>>(wb3, BR, R2, 512, 2304, 8192, 512, 8, 0);
        im2row_k<<<4608,256,0,stream>>>(R2, BR, 0, 2048, 512, 16, 16, 8, 8, 2, 4608);
        gemm_conv<<<256,256,0,stream>>>(wb4, BR, R1, 1024, 4608, 2048, 1024, 6, 0);

        row_mean64<ushort><<<8192,256,0,stream>>>(R1, lmean, 32768);
        head_sigmoid<<<3,256,0,stream>>>(lmean, clsw, clsb, locf, (float*)nullptr, 32);
        local_stream_max<<<1,256,0,stream>>>(locf, out_ls, 8);
    } else {
        // -------- f32 fallback --------
        float* ws = (float*)d_ws;
        float* bufA  = ws + 0;          // 8.4MB
        float* bufB  = ws + 2097152;    // 16.8MB
        float* act   = ws + 6291456;    // 2MB
        float* gmean = ws + 6815744;
        float* gst   = ws + 6823936;
        float* cam   = ws + 6824096;
        int*   top   = (int*)(ws + 6834336);
        float* xs    = ws + 6834368;
        float* ysn   = ws + 6838464;
        int*   box   = (int*)(ws + 6842560);
        float* lmean = ws + 6842688;
        float* locf  = ws + 6875456;

        run_stack_f32(x, 8, c1w, bng, bnb, bnm, bnv, w1, w2, w3, w4, bufA, bufB, act, stream);
        row_mean64<float><<<2048,256,0,stream>>>(act, gmean, 8192);
        head_sigmoid<<<1,256,0,stream>>>(gmean, clsw, clsb, gst, out_gs, 8);
        cam_kernel<<<40,256,0,stream>>>(act, clsw, clsb, cam, 8);
        resize_cam<<<10240,256,0,stream>>>(cam, out_cs, 8);
        score_maxred<<<160,256,0,stream>>>(out_cs, out_ws, out_hs, 8);
        topk4<<<1,64,0,stream>>>(gst, top, 8);
        gather_norm<<<64,128,0,stream>>>(out_ws, out_hs, top, xs, ysn, 8);
        objloc<<<1,64,0,stream>>>(xs, ysn, box, 8);
        crop_resize_k<<<6144,256,0,stream>>>(x, box, out_li, 8);

        for (int c = 0; c < 4; ++c) {
            const float* lin_c = out_li + (size_t)c*8*3*16384;
            run_stack_f32(lin_c, 8, c1w, bng, bnb, bnm, bnv, w1, w2, w3, w4, bufA, bufB, act, stream);
            row_mean64<float><<<2048,256,0,stream>>>(act, lmean + c*8192, 8192);
        }
        head_sigmoid<<<3,256,0,stream>>>(lmean, clsw, clsb, locf, (float*)nullptr, 32);
        local_stream_max<<<1,256,0,stream>>>(locf, out_ls, 8);
    }
}